// Round 1
// baseline (861.450 us; speedup 1.0000x reference)
//
#include <hip/hip_runtime.h>

#define NN 50000
#define NER 800000
#define NE 850000
#define MAXN 0.996f
#define MINNRM 1e-15f

__device__ __forceinline__ float wsum(float v){
#pragma unroll
  for (int m = 32; m >= 1; m >>= 1) v += __shfl_xor(v, m, 64);
  return v;
}
__device__ __forceinline__ float artanh_c(float t){
  t = fminf(t, 1.0f - 1e-7f);
  return 0.5f * (log1pf(t) - log1pf(-t));
}
__device__ __forceinline__ float lrelu(float t, float s){ return t >= 0.f ? t : s * t; }
__device__ __forceinline__ void onl_merge(float& m, float& s, float om, float os){
  float mn = fmaxf(m, om);
  s = s * __expf(m - mn) + os * __expf(om - mn);
  m = mn;
}

// ---- bias: hb = proj(expmap0(b)), plus |hb|^2 at hb[L] ----
__global__ void kbias(const float* __restrict__ b, int L, float* __restrict__ hb){
  __shared__ float red[256];
  int t = threadIdx.x;
  float v = (t < L) ? b[t] : 0.f;
  red[t] = v * v; __syncthreads();
  for (int s = 128; s; s >>= 1){ if (t < s) red[t] += red[t + s]; __syncthreads(); }
  float n  = fmaxf(sqrtf(red[0]), MINNRM);
  float un = tanhf(n);
  float nn = un;
  float f  = un / n;
  if (un > MAXN){ f = MAXN / n; nn = MAXN; }
  if (t < L) hb[t] = v * f;
  if (t == 0) hb[L] = nn * nn;
}

// ---- CSR build ----
__global__ void khist(const int* __restrict__ ei, int* __restrict__ cnt){
  int e = blockIdx.x * blockDim.x + threadIdx.x;
  if (e >= NE) return;
  int s = (e < NER) ? ei[e] : (e - NER);
  atomicAdd(&cnt[s], 1);
}

__global__ void kscan(int* __restrict__ cnt_cursor, int* __restrict__ rowptr){
  __shared__ int sh[1024];
  int t = threadIdx.x;
  const int CH = (NN + 1023) / 1024;
  int lo = t * CH, hi = min(lo + CH, NN);
  int s = 0;
  for (int i = lo; i < hi; i++) s += cnt_cursor[i];
  sh[t] = s; __syncthreads();
  for (int d = 1; d < 1024; d <<= 1){
    int v = (t >= d) ? sh[t - d] : 0;
    __syncthreads();
    sh[t] += v;
    __syncthreads();
  }
  int base = (t > 0) ? sh[t - 1] : 0;
  for (int i = lo; i < hi; i++){
    int c = cnt_cursor[i];
    rowptr[i] = base;
    cnt_cursor[i] = base;   // becomes fill cursor
    base += c;
  }
  if (t == 1023) rowptr[NN] = sh[1023];
}

__global__ void kfill(const int* __restrict__ ei, int* __restrict__ cursor, int* __restrict__ col){
  int e = blockIdx.x * blockDim.x + threadIdx.x;
  if (e >= NE) return;
  int s, d;
  if (e < NER){ s = ei[e]; d = ei[NER + e]; }
  else { s = e - NER; d = s; }
  int pos = atomicAdd(&cursor[s], 1);
  col[pos] = d;
}

// ---- K1: h0 = proj(expmap0(x @ Wl^T + bl)), wave per row ----
__global__ __launch_bounds__(256) void k_lin0(const float* __restrict__ x, const float* __restrict__ Wl,
                                              const float* __restrict__ bl, float* __restrict__ h0){
  __shared__ float w[64 * 130];
  for (int i = threadIdx.x; i < 64 * 128; i += 256){
    int o = i >> 7, k = i & 127;
    w[o * 130 + k] = Wl[i];
  }
  __syncthreads();
  int wave = threadIdx.x >> 6, lane = threadIdx.x & 63;
  int row = blockIdx.x * 4 + wave;
  if (row >= NN) return;
  const float* xr = x + (size_t)row * 128;
  float acc = 0.f;
#pragma unroll
  for (int k = 0; k < 128; k += 2){
    float2 xv = *(const float2*)(xr + k);
    float2 wv = *(const float2*)(&w[lane * 130 + k]);
    acc += xv.x * wv.x + xv.y * wv.y;
  }
  acc += bl[lane];
  float n  = fmaxf(sqrtf(wsum(acc * acc)), MINNRM);
  float un = tanhf(n);
  float f  = (un > MAXN) ? (MAXN / n) : (un / n);
  h0[(size_t)row * 64 + lane] = acc * f;
}

// ---- K2: hyp_linear layer1 + logmap0 + attention dot products ----
__global__ __launch_bounds__(256) void k_hlin1(const float* __restrict__ h0, const float* __restrict__ W1,
    const float* __restrict__ hb, const float* __restrict__ ai, const float* __restrict__ aj,
    float* __restrict__ ht1, float* __restrict__ s1i, float* __restrict__ s1j){
  __shared__ float w[128 * 66];
  for (int i = threadIdx.x; i < 128 * 64; i += 256){
    int o = i >> 6, k = i & 63;
    w[o * 66 + k] = W1[i];
  }
  __syncthreads();
  int wave = threadIdx.x >> 6, lane = threadIdx.x & 63;
  int row = blockIdx.x * 4 + wave;
  if (row >= NN) return;
  const float* xr = h0 + (size_t)row * 64;
  float xs = xr[lane];
  float xn = fmaxf(sqrtf(wsum(xs * xs)), MINNRM);
  float r_art = artanh_c(xn);
  float a0 = 0.f, a1 = 0.f;
#pragma unroll
  for (int k = 0; k < 64; k += 2){
    float2 xv = *(const float2*)(xr + k);
    float2 w0 = *(const float2*)(&w[lane * 66 + k]);
    float2 w1 = *(const float2*)(&w[(lane + 64) * 66 + k]);
    a0 += xv.x * w0.x + xv.y * w0.y;
    a1 += xv.x * w1.x + xv.y * w1.y;
  }
  float mxn = fmaxf(sqrtf(wsum(a0 * a0 + a1 * a1)), MINNRM);
  float tn  = tanhf(mxn / xn * r_art);
  float sc  = tn / mxn;
  float r0 = a0 * sc, r1 = a1 * sc;
  float rn = tn;
  if (rn > MAXN){ float f = MAXN / rn; r0 *= f; r1 *= f; rn = MAXN; }
  float a2 = rn * rn;
  float hv0 = hb[lane], hv1 = hb[lane + 64];
  float b2 = hb[128];
  float ab = wsum(r0 * hv0 + r1 * hv1);
  float co1 = 1.f + 2.f * ab + b2;
  float co2 = 1.f - a2;
  float den = fmaxf(1.f + 2.f * ab + a2 * b2, MINNRM);
  float h_0 = (co1 * r0 + co2 * hv0) / den;
  float h_1 = (co1 * r1 + co2 * hv1) / den;
  float hn = fmaxf(sqrtf(wsum(h_0 * h_0 + h_1 * h_1)), MINNRM);
  if (hn > MAXN){ float f = MAXN / hn; h_0 *= f; h_1 *= f; hn = MAXN; }
  float lf = artanh_c(hn) / hn;
  float t0 = h_0 * lf, t1 = h_1 * lf;
  ht1[(size_t)row * 128 + lane] = t0;
  ht1[(size_t)row * 128 + 64 + lane] = t1;
  // heads: o=lane -> head lane/32 in {0,1}; o=lane+64 -> head +2
  float pi0 = t0 * ai[lane], pi1 = t1 * ai[lane + 64];
  float pj0 = t0 * aj[lane], pj1 = t1 * aj[lane + 64];
#pragma unroll
  for (int m = 16; m >= 1; m >>= 1){
    pi0 += __shfl_xor(pi0, m, 64); pi1 += __shfl_xor(pi1, m, 64);
    pj0 += __shfl_xor(pj0, m, 64); pj1 += __shfl_xor(pj1, m, 64);
  }
  if (lane == 0){ s1i[row*4+0]=pi0; s1i[row*4+2]=pi1; s1j[row*4+0]=pj0; s1j[row*4+2]=pj1; }
  if (lane == 32){ s1i[row*4+1]=pi0; s1i[row*4+3]=pi1; s1j[row*4+1]=pj0; s1j[row*4+3]=pj1; }
}

// ---- K3: attention agg layer1 + hyp_act, wave per node ----
__global__ __launch_bounds__(256) void k_agg1(const int* __restrict__ rowptr, const int* __restrict__ col,
    const float* __restrict__ ht1, const float* __restrict__ s1i, const float* __restrict__ s1j,
    float* __restrict__ hact){
  int wave = threadIdx.x >> 6, lane = threadIdx.x & 63;
  int n = blockIdx.x * 4 + wave;
  if (n >= NN) return;
  int p0 = rowptr[n], p1 = rowptr[n + 1];
  float4 si = *(const float4*)(s1i + (size_t)n * 4);
  float m0=-1e30f,m1=-1e30f,m2=-1e30f,m3=-1e30f;
  float s0=0.f,s1=0.f,s2=0.f,s3=0.f;
  for (int e = p0 + lane; e < p1; e += 64){
    int d = col[e];
    float4 sj = *(const float4*)(s1j + (size_t)d * 4);
    float A0 = lrelu(si.x + sj.x, 0.2f);
    float A1 = lrelu(si.y + sj.y, 0.2f);
    float A2 = lrelu(si.z + sj.z, 0.2f);
    float A3 = lrelu(si.w + sj.w, 0.2f);
    onl_merge(m0, s0, A0, 1.f);
    onl_merge(m1, s1, A1, 1.f);
    onl_merge(m2, s2, A2, 1.f);
    onl_merge(m3, s3, A3, 1.f);
  }
#pragma unroll
  for (int mk = 32; mk >= 1; mk >>= 1){
    float om, os;
    om = __shfl_xor(m0, mk, 64); os = __shfl_xor(s0, mk, 64); onl_merge(m0, s0, om, os);
    om = __shfl_xor(m1, mk, 64); os = __shfl_xor(s1, mk, 64); onl_merge(m1, s1, om, os);
    om = __shfl_xor(m2, mk, 64); os = __shfl_xor(s2, mk, 64); onl_merge(m2, s2, om, os);
    om = __shfl_xor(m3, mk, 64); os = __shfl_xor(s3, mk, 64); onl_merge(m3, s3, om, os);
  }
  int h = lane >> 4;
  float mh  = (h==0)?m0:(h==1)?m1:(h==2)?m2:m3;
  float rdh = 1.f / (((h==0)?s0:(h==1)?s1:(h==2)?s2:s3) + 1e-16f);
  float sih = (h==0)?si.x:(h==1)?si.y:(h==2)?si.z:si.w;
  float acc0 = 0.f, acc1 = 0.f;
  int e = p0;
  for (; e + 1 < p1; e += 2){
    int d0 = col[e], d1 = col[e + 1];
    float sj0 = s1j[(size_t)d0 * 4 + h];
    float sj1 = s1j[(size_t)d1 * 4 + h];
    float2 v0 = *(const float2*)(ht1 + (size_t)d0 * 128 + 2 * lane);
    float2 v1 = *(const float2*)(ht1 + (size_t)d1 * 128 + 2 * lane);
    float wA = __expf(lrelu(sih + sj0, 0.2f) - mh) * rdh;
    float wB = __expf(lrelu(sih + sj1, 0.2f) - mh) * rdh;
    acc0 += wA * v0.x + wB * v1.x;
    acc1 += wA * v0.y + wB * v1.y;
  }
  if (e < p1){
    int d0 = col[e];
    float sj0 = s1j[(size_t)d0 * 4 + h];
    float2 v0 = *(const float2*)(ht1 + (size_t)d0 * 128 + 2 * lane);
    float wA = __expf(lrelu(sih + sj0, 0.2f) - mh) * rdh;
    acc0 += wA * v0.x; acc1 += wA * v0.y;
  }
  // proj(expmap0(acc)) -> logmap0 -> lrelu(0.01) -> proj(expmap0)
  float nn = fmaxf(sqrtf(wsum(acc0*acc0 + acc1*acc1)), MINNRM);
  float un = tanhf(nn);
  float f  = un / nn; float uN = un;
  if (un > MAXN){ f = MAXN / nn; uN = MAXN; }
  float lg = artanh_c(uN) / fmaxf(uN, MINNRM);
  float t0 = lrelu(acc0 * f * lg, 0.01f);
  float t1 = lrelu(acc1 * f * lg, 0.01f);
  float nn2 = fmaxf(sqrtf(wsum(t0*t0 + t1*t1)), MINNRM);
  float un2 = tanhf(nn2);
  float f2 = (un2 > MAXN) ? (MAXN / nn2) : (un2 / nn2);
  float2 o2; o2.x = t0 * f2; o2.y = t1 * f2;
  *(float2*)(hact + (size_t)n * 128 + 2 * lane) = o2;
}

// ---- K4: hyp_linear layer2 (256 outs, K=128) + logmap0 + s2 ----
__global__ __launch_bounds__(256) void k_hlin2(const float* __restrict__ hact, const float* __restrict__ W2,
    const float* __restrict__ hb, const float* __restrict__ ai, const float* __restrict__ aj,
    float* __restrict__ ht2, float* __restrict__ s2i, float* __restrict__ s2j){
  __shared__ float w[64 * 130];
  int wave = threadIdx.x >> 6, lane = threadIdx.x & 63;
  int row0 = blockIdx.x * 32 + wave * 8;
  float acc[8][4];
#pragma unroll
  for (int r = 0; r < 8; r++)
#pragma unroll
    for (int q = 0; q < 4; q++) acc[r][q] = 0.f;
  for (int q = 0; q < 4; q++){
    __syncthreads();
    for (int i = threadIdx.x; i < 64 * 128; i += 256){
      int o = i >> 7, k = i & 127;
      w[o * 130 + k] = W2[(size_t)(q * 64 + o) * 128 + k];
    }
    __syncthreads();
    for (int r = 0; r < 8; r++){
      int row = row0 + r; if (row >= NN) break;
      const float* xr = hact + (size_t)row * 128;
      float a = 0.f;
#pragma unroll 8
      for (int k = 0; k < 128; k += 2){
        float2 xv = *(const float2*)(xr + k);
        float2 wv = *(const float2*)(&w[lane * 130 + k]);
        a += xv.x * wv.x + xv.y * wv.y;
      }
      acc[r][q] = a;
    }
  }
  float b2 = hb[256];
  for (int r = 0; r < 8; r++){
    int row = row0 + r; if (row >= NN) break;
    const float* xr = hact + (size_t)row * 128;
    float x0 = xr[lane], x1 = xr[lane + 64];
    float xn = fmaxf(sqrtf(wsum(x0 * x0 + x1 * x1)), MINNRM);
    float r_art = artanh_c(xn);
    float msq = acc[r][0]*acc[r][0] + acc[r][1]*acc[r][1] + acc[r][2]*acc[r][2] + acc[r][3]*acc[r][3];
    float mxn = fmaxf(sqrtf(wsum(msq)), MINNRM);
    float tn = tanhf(mxn / xn * r_art);
    float sc = tn / mxn;
    float res0 = acc[r][0]*sc, res1 = acc[r][1]*sc, res2 = acc[r][2]*sc, res3 = acc[r][3]*sc;
    float rn = tn;
    if (rn > MAXN){ float f = MAXN / rn; res0*=f; res1*=f; res2*=f; res3*=f; rn = MAXN; }
    float a2 = rn * rn;
    float hb0 = hb[lane], hb1v = hb[64 + lane], hb2v = hb[128 + lane], hb3 = hb[192 + lane];
    float ab = wsum(res0*hb0 + res1*hb1v + res2*hb2v + res3*hb3);
    float co1 = 1.f + 2.f * ab + b2;
    float co2 = 1.f - a2;
    float den = fmaxf(1.f + 2.f * ab + a2 * b2, MINNRM);
    float h0v = (co1*res0 + co2*hb0) / den;
    float h1v = (co1*res1 + co2*hb1v) / den;
    float h2v = (co1*res2 + co2*hb2v) / den;
    float h3v = (co1*res3 + co2*hb3) / den;
    float hn = fmaxf(sqrtf(wsum(h0v*h0v + h1v*h1v + h2v*h2v + h3v*h3v)), MINNRM);
    if (hn > MAXN){ float f = MAXN / hn; h0v*=f; h1v*=f; h2v*=f; h3v*=f; hn = MAXN; }
    float lf = artanh_c(hn) / hn;
    float t0 = h0v*lf, t1 = h1v*lf, t2 = h2v*lf, t3 = h3v*lf;
    ht2[(size_t)row * 256 +       lane] = t0;
    ht2[(size_t)row * 256 +  64 + lane] = t1;
    ht2[(size_t)row * 256 + 128 + lane] = t2;
    ht2[(size_t)row * 256 + 192 + lane] = t3;
    float pi0 = wsum(t0 * ai[lane]);
    float pi1 = wsum(t1 * ai[64 + lane]);
    float pi2 = wsum(t2 * ai[128 + lane]);
    float pi3 = wsum(t3 * ai[192 + lane]);
    float pj0 = wsum(t0 * aj[lane]);
    float pj1 = wsum(t1 * aj[64 + lane]);
    float pj2 = wsum(t2 * aj[128 + lane]);
    float pj3 = wsum(t3 * aj[192 + lane]);
    if (lane == 0){
      s2i[row*4+0]=pi0; s2i[row*4+1]=pi1; s2i[row*4+2]=pi2; s2i[row*4+3]=pi3;
      s2j[row*4+0]=pj0; s2j[row*4+1]=pj1; s2j[row*4+2]=pj2; s2j[row*4+3]=pj3;
    }
  }
}

// ---- K5: attention agg layer2 (mean heads) + hyp_act + logmap0 -> out ----
__global__ __launch_bounds__(256) void k_agg2(const int* __restrict__ rowptr, const int* __restrict__ col,
    const float* __restrict__ ht2, const float* __restrict__ s2i, const float* __restrict__ s2j,
    float* __restrict__ out){
  int wave = threadIdx.x >> 6, lane = threadIdx.x & 63;
  int n = blockIdx.x * 4 + wave;
  if (n >= NN) return;
  int p0 = rowptr[n], p1 = rowptr[n + 1];
  float4 si = *(const float4*)(s2i + (size_t)n * 4);
  float m0=-1e30f,m1=-1e30f,m2=-1e30f,m3=-1e30f;
  float s0=0.f,s1=0.f,s2=0.f,s3=0.f;
  for (int e = p0 + lane; e < p1; e += 64){
    int d = col[e];
    float4 sj = *(const float4*)(s2j + (size_t)d * 4);
    onl_merge(m0, s0, lrelu(si.x + sj.x, 0.2f), 1.f);
    onl_merge(m1, s1, lrelu(si.y + sj.y, 0.2f), 1.f);
    onl_merge(m2, s2, lrelu(si.z + sj.z, 0.2f), 1.f);
    onl_merge(m3, s3, lrelu(si.w + sj.w, 0.2f), 1.f);
  }
#pragma unroll
  for (int mk = 32; mk >= 1; mk >>= 1){
    float om, os;
    om = __shfl_xor(m0, mk, 64); os = __shfl_xor(s0, mk, 64); onl_merge(m0, s0, om, os);
    om = __shfl_xor(m1, mk, 64); os = __shfl_xor(s1, mk, 64); onl_merge(m1, s1, om, os);
    om = __shfl_xor(m2, mk, 64); os = __shfl_xor(s2, mk, 64); onl_merge(m2, s2, om, os);
    om = __shfl_xor(m3, mk, 64); os = __shfl_xor(s3, mk, 64); onl_merge(m3, s3, om, os);
  }
  float rd0 = 1.f / (s0 + 1e-16f), rd1 = 1.f / (s1 + 1e-16f);
  float rd2 = 1.f / (s2 + 1e-16f), rd3 = 1.f / (s3 + 1e-16f);
  float a0=0.f, a1=0.f, a2v=0.f, a3=0.f;
  int e = p0;
  for (; e + 1 < p1; e += 2){
    int d0 = col[e], d1 = col[e + 1];
    float4 sjA = *(const float4*)(s2j + (size_t)d0 * 4);
    float4 sjB = *(const float4*)(s2j + (size_t)d1 * 4);
    const float* vA = ht2 + (size_t)d0 * 256 + lane;
    const float* vB = ht2 + (size_t)d1 * 256 + lane;
    float wA0 = __expf(lrelu(si.x + sjA.x, 0.2f) - m0) * rd0;
    float wA1 = __expf(lrelu(si.y + sjA.y, 0.2f) - m1) * rd1;
    float wA2 = __expf(lrelu(si.z + sjA.z, 0.2f) - m2) * rd2;
    float wA3 = __expf(lrelu(si.w + sjA.w, 0.2f) - m3) * rd3;
    float wB0 = __expf(lrelu(si.x + sjB.x, 0.2f) - m0) * rd0;
    float wB1 = __expf(lrelu(si.y + sjB.y, 0.2f) - m1) * rd1;
    float wB2 = __expf(lrelu(si.z + sjB.z, 0.2f) - m2) * rd2;
    float wB3 = __expf(lrelu(si.w + sjB.w, 0.2f) - m3) * rd3;
    a0 += wA0 * vA[0]   + wB0 * vB[0];
    a1 += wA1 * vA[64]  + wB1 * vB[64];
    a2v+= wA2 * vA[128] + wB2 * vB[128];
    a3 += wA3 * vA[192] + wB3 * vB[192];
  }
  if (e < p1){
    int d0 = col[e];
    float4 sjA = *(const float4*)(s2j + (size_t)d0 * 4);
    const float* vA = ht2 + (size_t)d0 * 256 + lane;
    a0 += __expf(lrelu(si.x + sjA.x, 0.2f) - m0) * rd0 * vA[0];
    a1 += __expf(lrelu(si.y + sjA.y, 0.2f) - m1) * rd1 * vA[64];
    a2v+= __expf(lrelu(si.z + sjA.z, 0.2f) - m2) * rd2 * vA[128];
    a3 += __expf(lrelu(si.w + sjA.w, 0.2f) - m3) * rd3 * vA[192];
  }
  float mean = 0.25f * (a0 + a1 + a2v + a3);
  float nn = fmaxf(sqrtf(wsum(mean * mean)), MINNRM);
  float un = tanhf(nn);
  float f = un / nn; float uN = un;
  if (un > MAXN){ f = MAXN / nn; uN = MAXN; }
  float lg = artanh_c(uN) / fmaxf(uN, MINNRM);
  float t = lrelu(mean * f * lg, 0.01f);
  float nn2 = fmaxf(sqrtf(wsum(t * t)), MINNRM);
  float un2 = tanhf(nn2);
  float f2 = (un2 > MAXN) ? (MAXN / nn2) : (un2 / nn2);
  float uN2 = fminf(un2, MAXN);
  float lg2 = artanh_c(uN2) / fmaxf(uN2, MINNRM);
  out[(size_t)n * 64 + lane] = t * f2 * lg2;
}

extern "C" void kernel_launch(void* const* d_in, const int* in_sizes, int n_in,
                              void* d_out, int out_size, void* d_ws, size_t ws_size,
                              hipStream_t stream){
  const float* x   = (const float*)d_in[0];
  const float* Wl  = (const float*)d_in[1];
  const float* bl  = (const float*)d_in[2];
  const float* W1  = (const float*)d_in[3];
  const float* b1  = (const float*)d_in[4];
  const float* ai1 = (const float*)d_in[5];
  const float* aj1 = (const float*)d_in[6];
  const float* W2  = (const float*)d_in[7];
  const float* b2  = (const float*)d_in[8];
  const float* ai2 = (const float*)d_in[9];
  const float* aj2 = (const float*)d_in[10];
  const int*   ei  = (const int*)d_in[11];
  float* out = (float*)d_out;
  float* ws  = (float*)d_ws;

  float* h0   = ws;                   // 3.2M floats
  float* ht1  = ws + 3200000;         // 6.4M
  float* ht2  = ws;                   // 12.8M (aliases h0+ht1, both dead by then)
  float* hact = ws + 12800000;        // 6.4M
  float* s1i  = ws + 19200000;        // 200K
  float* s1j  = ws + 19400000;
  float* s2i  = ws + 19600000;
  float* s2j  = ws + 19800000;
  float* hb1  = ws + 20000000;        // 129
  float* hb2  = ws + 20000132;        // 257
  int* rowptr = (int*)(ws + 20000392);   // NN+1
  int* cnt    = rowptr + NN + 1;         // NN (doubles as cursor)
  int* col    = cnt + NN;                // NE

  hipMemsetAsync(cnt, 0, NN * sizeof(int), stream);
  kbias<<<1, 256, 0, stream>>>(b1, 128, hb1);
  kbias<<<1, 256, 0, stream>>>(b2, 256, hb2);
  khist<<<(NE + 255) / 256, 256, 0, stream>>>(ei, cnt);
  kscan<<<1, 1024, 0, stream>>>(cnt, rowptr);
  kfill<<<(NE + 255) / 256, 256, 0, stream>>>(ei, cnt, col);
  k_lin0<<<(NN + 3) / 4, 256, 0, stream>>>(x, Wl, bl, h0);
  k_hlin1<<<(NN + 3) / 4, 256, 0, stream>>>(h0, W1, hb1, ai1, aj1, ht1, s1i, s1j);
  k_agg1<<<(NN + 3) / 4, 256, 0, stream>>>(rowptr, col, ht1, s1i, s1j, hact);
  k_hlin2<<<(NN + 31) / 32, 256, 0, stream>>>(hact, W2, hb2, ai2, aj2, ht2, s2i, s2j);
  k_agg2<<<(NN + 3) / 4, 256, 0, stream>>>(rowptr, col, ht2, s2i, s2j, out);
}

// Round 2
// 664.793 us; speedup vs baseline: 1.2958x; 1.2958x over previous
//
#include <hip/hip_runtime.h>

#define NN 50000
#define NER 800000
#define NE 850000
#define MAXN 0.996f
#define MINNRM 1e-15f

__device__ __forceinline__ float wsum(float v){
#pragma unroll
  for (int m = 32; m >= 1; m >>= 1) v += __shfl_xor(v, m, 64);
  return v;
}
__device__ __forceinline__ float artanh_c(float t){
  t = fminf(t, 1.0f - 1e-7f);
  return 0.5f * (log1pf(t) - log1pf(-t));
}
__device__ __forceinline__ float lrelu(float t, float s){ return t >= 0.f ? t : s * t; }
__device__ __forceinline__ void onl_merge(float& m, float& s, float om, float os){
  float mn = fmaxf(m, om);
  s = s * __expf(m - mn) + os * __expf(om - mn);
  m = mn;
}

// ---- bias: hb = proj(expmap0(b)), plus |hb|^2 at hb[L] ----
__global__ void kbias(const float* __restrict__ b, int L, float* __restrict__ hb){
  __shared__ float red[256];
  int t = threadIdx.x;
  float v = (t < L) ? b[t] : 0.f;
  red[t] = v * v; __syncthreads();
  for (int s = 128; s; s >>= 1){ if (t < s) red[t] += red[t + s]; __syncthreads(); }
  float n  = fmaxf(sqrtf(red[0]), MINNRM);
  float un = tanhf(n);
  float nn = un;
  float f  = un / n;
  if (un > MAXN){ f = MAXN / n; nn = MAXN; }
  if (t < L) hb[t] = v * f;
  if (t == 0) hb[L] = nn * nn;
}

// ---- CSR build ----
__global__ void khist(const int* __restrict__ ei, int* __restrict__ cnt){
  int e = blockIdx.x * blockDim.x + threadIdx.x;
  if (e >= NE) return;
  int s = (e < NER) ? ei[e] : (e - NER);
  atomicAdd(&cnt[s], 1);
}

__global__ void kscan(int* __restrict__ cnt_cursor, int* __restrict__ rowptr){
  __shared__ int sh[1024];
  int t = threadIdx.x;
  const int CH = (NN + 1023) / 1024;
  int lo = t * CH, hi = min(lo + CH, NN);
  int s = 0;
  for (int i = lo; i < hi; i++) s += cnt_cursor[i];
  sh[t] = s; __syncthreads();
  for (int d = 1; d < 1024; d <<= 1){
    int v = (t >= d) ? sh[t - d] : 0;
    __syncthreads();
    sh[t] += v;
    __syncthreads();
  }
  int base = (t > 0) ? sh[t - 1] : 0;
  for (int i = lo; i < hi; i++){
    int c = cnt_cursor[i];
    rowptr[i] = base;
    cnt_cursor[i] = base;   // becomes fill cursor
    base += c;
  }
  if (t == 1023) rowptr[NN] = sh[1023];
}

__global__ void kfill(const int* __restrict__ ei, int* __restrict__ cursor, int* __restrict__ col){
  int e = blockIdx.x * blockDim.x + threadIdx.x;
  if (e >= NE) return;
  int s, d;
  if (e < NER){ s = ei[e]; d = ei[NER + e]; }
  else { s = e - NER; d = s; }
  int pos = atomicAdd(&cursor[s], 1);
  col[pos] = d;
}

// ---- G0 fused: h0 = proj(expmap0(x @ Wl^T + bl)) + xn0, reg-blocked GEMM ----
// block 256 thr = 4 waves, BM=256 rows, N=64, K=128. Wave w: rows w*64..+63 (all 64 cols).
// lane 8x8 grid: 8 rows x 8 cols micro-tile -> full output row within one 8-lane group.
__global__ __launch_bounds__(256) void k_g0(const float* __restrict__ x, const float* __restrict__ Wl,
                                            const float* __restrict__ bl, float* __restrict__ h0,
                                            float* __restrict__ xn0){
  __shared__ float As[32][256];
  __shared__ float Bs[32][64];
  int tid = threadIdx.x;
  int wave = tid >> 6, lane = tid & 63;
  int lr = lane >> 3, lc = lane & 7;
  int row0 = blockIdx.x * 256;
  int r0 = wave * 64 + lr * 8;
  int c0 = lc * 8;
  float acc[8][8] = {};
  for (int k0 = 0; k0 < 128; k0 += 32){
    __syncthreads();
    for (int f = tid; f < 256 * 8; f += 256){
      int m = f >> 3, ko = (f & 7) * 4;
      int row = row0 + m;
      float4 v = make_float4(0.f,0.f,0.f,0.f);
      if (row < NN) v = *(const float4*)(x + (size_t)row * 128 + k0 + ko);
      As[ko+0][m]=v.x; As[ko+1][m]=v.y; As[ko+2][m]=v.z; As[ko+3][m]=v.w;
    }
    for (int f = tid; f < 64 * 8; f += 256){
      int n = f >> 3, ko = (f & 7) * 4;
      float4 v = *(const float4*)(Wl + (size_t)n * 128 + k0 + ko);
      Bs[ko+0][n]=v.x; Bs[ko+1][n]=v.y; Bs[ko+2][n]=v.z; Bs[ko+3][n]=v.w;
    }
    __syncthreads();
#pragma unroll 4
    for (int k = 0; k < 32; k++){
      float a[8], b[8];
      *(float4*)&a[0] = *(const float4*)&As[k][r0];
      *(float4*)&a[4] = *(const float4*)&As[k][r0+4];
      *(float4*)&b[0] = *(const float4*)&Bs[k][c0];
      *(float4*)&b[4] = *(const float4*)&Bs[k][c0+4];
#pragma unroll
      for (int i = 0; i < 8; i++)
#pragma unroll
        for (int j = 0; j < 8; j++)
          acc[i][j] = fmaf(a[i], b[j], acc[i][j]);
    }
  }
  float bb[8];
  *(float4*)&bb[0] = *(const float4*)(bl + c0);
  *(float4*)&bb[4] = *(const float4*)(bl + c0 + 4);
#pragma unroll
  for (int i = 0; i < 8; i++){
    float rs = 0.f;
#pragma unroll
    for (int j = 0; j < 8; j++){ acc[i][j] += bb[j]; rs = fmaf(acc[i][j], acc[i][j], rs); }
    rs += __shfl_xor(rs, 1, 64);
    rs += __shfl_xor(rs, 2, 64);
    rs += __shfl_xor(rs, 4, 64);
    float n  = fmaxf(sqrtf(rs), MINNRM);
    float un = tanhf(n);
    float f, nm;
    if (un > MAXN){ f = MAXN / n; nm = MAXN; } else { f = un / n; nm = un; }
    int row = row0 + r0 + i;
    if (row < NN){
#pragma unroll
      for (int j = 0; j < 8; j++) acc[i][j] *= f;
      float* cp = h0 + (size_t)row * 64 + c0;
      *(float4*)cp     = *(float4*)&acc[i][0];
      *(float4*)(cp+4) = *(float4*)&acc[i][4];
      if (lc == 0) xn0[row] = nm;
    }
  }
}

// ---- generic raw GEMM: C[M x N] = A[M x K] @ B[N x K]^T ----
// 4 waves in WR x WC grid of 64x64 wave tiles; per-lane 8x8 micro-tile.
template<int N, int K, int WR, int WC>
__global__ __launch_bounds__(256) void kgemm(const float* __restrict__ A, const float* __restrict__ B,
                                             float* __restrict__ C, int M){
  constexpr int BM = WR * 64;
  __shared__ float As[32][BM];
  __shared__ float Bs[32][N];
  int tid = threadIdx.x;
  int wave = tid >> 6, lane = tid & 63;
  int wr = wave / WC, wc = wave % WC;
  int lr = lane >> 3, lc = lane & 7;
  int row0 = blockIdx.x * BM;
  int r0 = wr * 64 + lr * 8;
  int c0 = wc * 64 + lc * 8;
  float acc[8][8] = {};
  for (int k0 = 0; k0 < K; k0 += 32){
    __syncthreads();
    for (int f = tid; f < BM * 8; f += 256){
      int m = f >> 3, ko = (f & 7) * 4;
      int row = row0 + m;
      float4 v = make_float4(0.f,0.f,0.f,0.f);
      if (row < M) v = *(const float4*)(A + (size_t)row * K + k0 + ko);
      As[ko+0][m]=v.x; As[ko+1][m]=v.y; As[ko+2][m]=v.z; As[ko+3][m]=v.w;
    }
    for (int f = tid; f < N * 8; f += 256){
      int n = f >> 3, ko = (f & 7) * 4;
      float4 v = *(const float4*)(B + (size_t)n * K + k0 + ko);
      Bs[ko+0][n]=v.x; Bs[ko+1][n]=v.y; Bs[ko+2][n]=v.z; Bs[ko+3][n]=v.w;
    }
    __syncthreads();
#pragma unroll 4
    for (int k = 0; k < 32; k++){
      float a[8], b[8];
      *(float4*)&a[0] = *(const float4*)&As[k][r0];
      *(float4*)&a[4] = *(const float4*)&As[k][r0+4];
      *(float4*)&b[0] = *(const float4*)&Bs[k][c0];
      *(float4*)&b[4] = *(const float4*)&Bs[k][c0+4];
#pragma unroll
      for (int i = 0; i < 8; i++)
#pragma unroll
        for (int j = 0; j < 8; j++)
          acc[i][j] = fmaf(a[i], b[j], acc[i][j]);
    }
  }
#pragma unroll
  for (int i = 0; i < 8; i++){
    int row = row0 + r0 + i;
    if (row < M){
      float* cp = C + (size_t)row * N + c0;
      *(float4*)cp     = *(float4*)&acc[i][0];
      *(float4*)(cp+4) = *(float4*)&acc[i][4];
    }
  }
}

// ---- ep1: in-place mx1 -> ht1 (mobius scale, +hb, proj, logmap0) + s1 dots ----
__global__ __launch_bounds__(256) void ep1(float* __restrict__ mx1, const float* __restrict__ xn0,
    const float* __restrict__ hb, const float* __restrict__ ai, const float* __restrict__ aj,
    float* __restrict__ s1i, float* __restrict__ s1j){
  int wave = threadIdx.x >> 6, lane = threadIdx.x & 63;
  int row = blockIdx.x * 4 + wave;
  if (row >= NN) return;
  size_t base = (size_t)row * 128;
  float a0 = mx1[base + lane], a1 = mx1[base + 64 + lane];
  float xn = fmaxf(xn0[row], MINNRM);
  float r_art = artanh_c(xn);
  float mxn = fmaxf(sqrtf(wsum(a0 * a0 + a1 * a1)), MINNRM);
  float tn  = tanhf(mxn / xn * r_art);
  float sc  = tn / mxn;
  float r0 = a0 * sc, r1 = a1 * sc;
  float rn = tn;
  if (rn > MAXN){ float f = MAXN / rn; r0 *= f; r1 *= f; rn = MAXN; }
  float a2 = rn * rn;
  float hv0 = hb[lane], hv1 = hb[lane + 64];
  float b2 = hb[128];
  float ab = wsum(r0 * hv0 + r1 * hv1);
  float co1 = 1.f + 2.f * ab + b2;
  float co2 = 1.f - a2;
  float den = fmaxf(1.f + 2.f * ab + a2 * b2, MINNRM);
  float h_0 = (co1 * r0 + co2 * hv0) / den;
  float h_1 = (co1 * r1 + co2 * hv1) / den;
  float hn = fmaxf(sqrtf(wsum(h_0 * h_0 + h_1 * h_1)), MINNRM);
  if (hn > MAXN){ float f = MAXN / hn; h_0 *= f; h_1 *= f; hn = MAXN; }
  float lf = artanh_c(hn) / hn;
  float t0 = h_0 * lf, t1 = h_1 * lf;
  mx1[base + lane] = t0;
  mx1[base + 64 + lane] = t1;
  float pi0 = t0 * ai[lane], pi1 = t1 * ai[lane + 64];
  float pj0 = t0 * aj[lane], pj1 = t1 * aj[lane + 64];
#pragma unroll
  for (int m = 16; m >= 1; m >>= 1){
    pi0 += __shfl_xor(pi0, m, 64); pi1 += __shfl_xor(pi1, m, 64);
    pj0 += __shfl_xor(pj0, m, 64); pj1 += __shfl_xor(pj1, m, 64);
  }
  if (lane == 0){ s1i[row*4+0]=pi0; s1i[row*4+2]=pi1; s1j[row*4+0]=pj0; s1j[row*4+2]=pj1; }
  if (lane == 32){ s1i[row*4+1]=pi0; s1i[row*4+3]=pi1; s1j[row*4+1]=pj0; s1j[row*4+3]=pj1; }
}

// ---- K3: attention agg layer1 + hyp_act, wave per node; also writes ||hact|| ----
__global__ __launch_bounds__(256) void k_agg1(const int* __restrict__ rowptr, const int* __restrict__ col,
    const float* __restrict__ ht1, const float* __restrict__ s1i, const float* __restrict__ s1j,
    float* __restrict__ hact, float* __restrict__ xn1){
  int wave = threadIdx.x >> 6, lane = threadIdx.x & 63;
  int n = blockIdx.x * 4 + wave;
  if (n >= NN) return;
  int p0 = rowptr[n], p1 = rowptr[n + 1];
  float4 si = *(const float4*)(s1i + (size_t)n * 4);
  float m0=-1e30f,m1=-1e30f,m2=-1e30f,m3=-1e30f;
  float s0=0.f,s1=0.f,s2=0.f,s3=0.f;
  for (int e = p0 + lane; e < p1; e += 64){
    int d = col[e];
    float4 sj = *(const float4*)(s1j + (size_t)d * 4);
    onl_merge(m0, s0, lrelu(si.x + sj.x, 0.2f), 1.f);
    onl_merge(m1, s1, lrelu(si.y + sj.y, 0.2f), 1.f);
    onl_merge(m2, s2, lrelu(si.z + sj.z, 0.2f), 1.f);
    onl_merge(m3, s3, lrelu(si.w + sj.w, 0.2f), 1.f);
  }
#pragma unroll
  for (int mk = 32; mk >= 1; mk >>= 1){
    float om, os;
    om = __shfl_xor(m0, mk, 64); os = __shfl_xor(s0, mk, 64); onl_merge(m0, s0, om, os);
    om = __shfl_xor(m1, mk, 64); os = __shfl_xor(s1, mk, 64); onl_merge(m1, s1, om, os);
    om = __shfl_xor(m2, mk, 64); os = __shfl_xor(s2, mk, 64); onl_merge(m2, s2, om, os);
    om = __shfl_xor(m3, mk, 64); os = __shfl_xor(s3, mk, 64); onl_merge(m3, s3, om, os);
  }
  int h = lane >> 4;
  float mh  = (h==0)?m0:(h==1)?m1:(h==2)?m2:m3;
  float rdh = 1.f / (((h==0)?s0:(h==1)?s1:(h==2)?s2:s3) + 1e-16f);
  float sih = (h==0)?si.x:(h==1)?si.y:(h==2)?si.z:si.w;
  float acc0 = 0.f, acc1 = 0.f;
  int e = p0;
  for (; e + 1 < p1; e += 2){
    int d0 = col[e], d1 = col[e + 1];
    float sj0 = s1j[(size_t)d0 * 4 + h];
    float sj1 = s1j[(size_t)d1 * 4 + h];
    float2 v0 = *(const float2*)(ht1 + (size_t)d0 * 128 + 2 * lane);
    float2 v1 = *(const float2*)(ht1 + (size_t)d1 * 128 + 2 * lane);
    float wA = __expf(lrelu(sih + sj0, 0.2f) - mh) * rdh;
    float wB = __expf(lrelu(sih + sj1, 0.2f) - mh) * rdh;
    acc0 += wA * v0.x + wB * v1.x;
    acc1 += wA * v0.y + wB * v1.y;
  }
  if (e < p1){
    int d0 = col[e];
    float sj0 = s1j[(size_t)d0 * 4 + h];
    float2 v0 = *(const float2*)(ht1 + (size_t)d0 * 128 + 2 * lane);
    float wA = __expf(lrelu(sih + sj0, 0.2f) - mh) * rdh;
    acc0 += wA * v0.x; acc1 += wA * v0.y;
  }
  float nn = fmaxf(sqrtf(wsum(acc0*acc0 + acc1*acc1)), MINNRM);
  float un = tanhf(nn);
  float f  = un / nn; float uN = un;
  if (un > MAXN){ f = MAXN / nn; uN = MAXN; }
  float lg = artanh_c(uN) / fmaxf(uN, MINNRM);
  float t0 = lrelu(acc0 * f * lg, 0.01f);
  float t1 = lrelu(acc1 * f * lg, 0.01f);
  float nn2 = fmaxf(sqrtf(wsum(t0*t0 + t1*t1)), MINNRM);
  float un2 = tanhf(nn2);
  float f2, nm2;
  if (un2 > MAXN){ f2 = MAXN / nn2; nm2 = MAXN; } else { f2 = un2 / nn2; nm2 = un2; }
  float2 o2; o2.x = t0 * f2; o2.y = t1 * f2;
  *(float2*)(hact + (size_t)n * 128 + 2 * lane) = o2;
  if (lane == 0) xn1[n] = nm2;
}

// ---- ep2: in-place mx2 -> ht2 + s2 dots ----
__global__ __launch_bounds__(256) void ep2(float* __restrict__ mx2, const float* __restrict__ xn1,
    const float* __restrict__ hb, const float* __restrict__ ai, const float* __restrict__ aj,
    float* __restrict__ s2i, float* __restrict__ s2j){
  int wave = threadIdx.x >> 6, lane = threadIdx.x & 63;
  int row = blockIdx.x * 4 + wave;
  if (row >= NN) return;
  size_t base = (size_t)row * 256;
  float v0 = mx2[base + lane], v1 = mx2[base + 64 + lane];
  float v2 = mx2[base + 128 + lane], v3 = mx2[base + 192 + lane];
  float xn = fmaxf(xn1[row], MINNRM);
  float r_art = artanh_c(xn);
  float mxn = fmaxf(sqrtf(wsum(v0*v0 + v1*v1 + v2*v2 + v3*v3)), MINNRM);
  float tn = tanhf(mxn / xn * r_art);
  float sc = tn / mxn;
  float res0 = v0*sc, res1 = v1*sc, res2 = v2*sc, res3 = v3*sc;
  float rn = tn;
  if (rn > MAXN){ float f = MAXN / rn; res0*=f; res1*=f; res2*=f; res3*=f; rn = MAXN; }
  float a2 = rn * rn;
  float hb0 = hb[lane], hb1v = hb[64 + lane], hb2v = hb[128 + lane], hb3 = hb[192 + lane];
  float b2 = hb[256];
  float ab = wsum(res0*hb0 + res1*hb1v + res2*hb2v + res3*hb3);
  float co1 = 1.f + 2.f * ab + b2;
  float co2 = 1.f - a2;
  float den = fmaxf(1.f + 2.f * ab + a2 * b2, MINNRM);
  float h0v = (co1*res0 + co2*hb0) / den;
  float h1v = (co1*res1 + co2*hb1v) / den;
  float h2v = (co1*res2 + co2*hb2v) / den;
  float h3v = (co1*res3 + co2*hb3) / den;
  float hn = fmaxf(sqrtf(wsum(h0v*h0v + h1v*h1v + h2v*h2v + h3v*h3v)), MINNRM);
  if (hn > MAXN){ float f = MAXN / hn; h0v*=f; h1v*=f; h2v*=f; h3v*=f; hn = MAXN; }
  float lf = artanh_c(hn) / hn;
  float t0 = h0v*lf, t1 = h1v*lf, t2 = h2v*lf, t3 = h3v*lf;
  mx2[base +       lane] = t0;
  mx2[base +  64 + lane] = t1;
  mx2[base + 128 + lane] = t2;
  mx2[base + 192 + lane] = t3;
  float pi0 = wsum(t0 * ai[lane]);
  float pi1 = wsum(t1 * ai[64 + lane]);
  float pi2 = wsum(t2 * ai[128 + lane]);
  float pi3 = wsum(t3 * ai[192 + lane]);
  float pj0 = wsum(t0 * aj[lane]);
  float pj1 = wsum(t1 * aj[64 + lane]);
  float pj2 = wsum(t2 * aj[128 + lane]);
  float pj3 = wsum(t3 * aj[192 + lane]);
  if (lane == 0){
    s2i[row*4+0]=pi0; s2i[row*4+1]=pi1; s2i[row*4+2]=pi2; s2i[row*4+3]=pi3;
    s2j[row*4+0]=pj0; s2j[row*4+1]=pj1; s2j[row*4+2]=pj2; s2j[row*4+3]=pj3;
  }
}

// ---- K5: attention agg layer2 (mean heads) + hyp_act + logmap0 -> out ----
__global__ __launch_bounds__(256) void k_agg2(const int* __restrict__ rowptr, const int* __restrict__ col,
    const float* __restrict__ ht2, const float* __restrict__ s2i, const float* __restrict__ s2j,
    float* __restrict__ out){
  int wave = threadIdx.x >> 6, lane = threadIdx.x & 63;
  int n = blockIdx.x * 4 + wave;
  if (n >= NN) return;
  int p0 = rowptr[n], p1 = rowptr[n + 1];
  float4 si = *(const float4*)(s2i + (size_t)n * 4);
  float m0=-1e30f,m1=-1e30f,m2=-1e30f,m3=-1e30f;
  float s0=0.f,s1=0.f,s2=0.f,s3=0.f;
  for (int e = p0 + lane; e < p1; e += 64){
    int d = col[e];
    float4 sj = *(const float4*)(s2j + (size_t)d * 4);
    onl_merge(m0, s0, lrelu(si.x + sj.x, 0.2f), 1.f);
    onl_merge(m1, s1, lrelu(si.y + sj.y, 0.2f), 1.f);
    onl_merge(m2, s2, lrelu(si.z + sj.z, 0.2f), 1.f);
    onl_merge(m3, s3, lrelu(si.w + sj.w, 0.2f), 1.f);
  }
#pragma unroll
  for (int mk = 32; mk >= 1; mk >>= 1){
    float om, os;
    om = __shfl_xor(m0, mk, 64); os = __shfl_xor(s0, mk, 64); onl_merge(m0, s0, om, os);
    om = __shfl_xor(m1, mk, 64); os = __shfl_xor(s1, mk, 64); onl_merge(m1, s1, om, os);
    om = __shfl_xor(m2, mk, 64); os = __shfl_xor(s2, mk, 64); onl_merge(m2, s2, om, os);
    om = __shfl_xor(m3, mk, 64); os = __shfl_xor(s3, mk, 64); onl_merge(m3, s3, om, os);
  }
  float rd0 = 1.f / (s0 + 1e-16f), rd1 = 1.f / (s1 + 1e-16f);
  float rd2 = 1.f / (s2 + 1e-16f), rd3 = 1.f / (s3 + 1e-16f);
  float a0=0.f, a1=0.f, a2v=0.f, a3=0.f;
  int e = p0;
  for (; e + 1 < p1; e += 2){
    int d0 = col[e], d1 = col[e + 1];
    float4 sjA = *(const float4*)(s2j + (size_t)d0 * 4);
    float4 sjB = *(const float4*)(s2j + (size_t)d1 * 4);
    const float* vA = ht2 + (size_t)d0 * 256 + lane;
    const float* vB = ht2 + (size_t)d1 * 256 + lane;
    float wA0 = __expf(lrelu(si.x + sjA.x, 0.2f) - m0) * rd0;
    float wA1 = __expf(lrelu(si.y + sjA.y, 0.2f) - m1) * rd1;
    float wA2 = __expf(lrelu(si.z + sjA.z, 0.2f) - m2) * rd2;
    float wA3 = __expf(lrelu(si.w + sjA.w, 0.2f) - m3) * rd3;
    float wB0 = __expf(lrelu(si.x + sjB.x, 0.2f) - m0) * rd0;
    float wB1 = __expf(lrelu(si.y + sjB.y, 0.2f) - m1) * rd1;
    float wB2 = __expf(lrelu(si.z + sjB.z, 0.2f) - m2) * rd2;
    float wB3 = __expf(lrelu(si.w + sjB.w, 0.2f) - m3) * rd3;
    a0 += wA0 * vA[0]   + wB0 * vB[0];
    a1 += wA1 * vA[64]  + wB1 * vB[64];
    a2v+= wA2 * vA[128] + wB2 * vB[128];
    a3 += wA3 * vA[192] + wB3 * vB[192];
  }
  if (e < p1){
    int d0 = col[e];
    float4 sjA = *(const float4*)(s2j + (size_t)d0 * 4);
    const float* vA = ht2 + (size_t)d0 * 256 + lane;
    a0 += __expf(lrelu(si.x + sjA.x, 0.2f) - m0) * rd0 * vA[0];
    a1 += __expf(lrelu(si.y + sjA.y, 0.2f) - m1) * rd1 * vA[64];
    a2v+= __expf(lrelu(si.z + sjA.z, 0.2f) - m2) * rd2 * vA[128];
    a3 += __expf(lrelu(si.w + sjA.w, 0.2f) - m3) * rd3 * vA[192];
  }
  float mean = 0.25f * (a0 + a1 + a2v + a3);
  float nn = fmaxf(sqrtf(wsum(mean * mean)), MINNRM);
  float un = tanhf(nn);
  float f = un / nn; float uN = un;
  if (un > MAXN){ f = MAXN / nn; uN = MAXN; }
  float lg = artanh_c(uN) / fmaxf(uN, MINNRM);
  float t = lrelu(mean * f * lg, 0.01f);
  float nn2 = fmaxf(sqrtf(wsum(t * t)), MINNRM);
  float un2 = tanhf(nn2);
  float f2 = (un2 > MAXN) ? (MAXN / nn2) : (un2 / nn2);
  float uN2 = fminf(un2, MAXN);
  float lg2 = artanh_c(uN2) / fmaxf(uN2, MINNRM);
  out[(size_t)n * 64 + lane] = t * f2 * lg2;
}

extern "C" void kernel_launch(void* const* d_in, const int* in_sizes, int n_in,
                              void* d_out, int out_size, void* d_ws, size_t ws_size,
                              hipStream_t stream){
  const float* x   = (const float*)d_in[0];
  const float* Wl  = (const float*)d_in[1];
  const float* bl  = (const float*)d_in[2];
  const float* W1  = (const float*)d_in[3];
  const float* b1  = (const float*)d_in[4];
  const float* ai1 = (const float*)d_in[5];
  const float* aj1 = (const float*)d_in[6];
  const float* W2  = (const float*)d_in[7];
  const float* b2  = (const float*)d_in[8];
  const float* ai2 = (const float*)d_in[9];
  const float* aj2 = (const float*)d_in[10];
  const int*   ei  = (const int*)d_in[11];
  float* out = (float*)d_out;
  float* ws  = (float*)d_ws;

  // slab layout (floats), in-place aliasing:
  //  h0        [0,        3.2M)   dead after G1
  //  mx1/ht1   [3.2M,     9.6M)   ep1 in-place; dead after agg1
  //  hact      [9.6M,     16M)    dead after G2
  //  mx2/ht2   [0,        12.8M)  written by G2 (h0, mx1/ht1 dead by then); ep2 in-place
  float* h0   = ws;
  float* mx1  = ws + 3200000;   // = ht1
  float* hact = ws + 9600000;
  float* mx2  = ws;             // = ht2
  float* xn0  = ws + 16000000;  // 50K
  float* xn1  = ws + 16050000;  // 50K
  float* s1i  = ws + 16100000;  // 200K  (= s2i, s1 dead before ep2 writes)
  float* s1j  = ws + 16300000;  // 200K  (= s2j)
  float* hb1  = ws + 16500000;  // 129 (pad 132)
  float* hb2  = ws + 16500132;  // 257
  int* rowptr = (int*)(ws + 16500392);   // NN+1
  int* cnt    = rowptr + NN + 1;         // NN (doubles as cursor)
  int* col    = cnt + NN;                // NE

  hipMemsetAsync(cnt, 0, NN * sizeof(int), stream);
  kbias<<<1, 256, 0, stream>>>(b1, 128, hb1);
  kbias<<<1, 256, 0, stream>>>(b2, 256, hb2);
  khist<<<(NE + 255) / 256, 256, 0, stream>>>(ei, cnt);
  kscan<<<1, 1024, 0, stream>>>(cnt, rowptr);
  kfill<<<(NE + 255) / 256, 256, 0, stream>>>(ei, cnt, col);
  k_g0<<<(NN + 255) / 256, 256, 0, stream>>>(x, Wl, bl, h0, xn0);
  kgemm<128, 64, 2, 2><<<(NN + 127) / 128, 256, 0, stream>>>(h0, W1, mx1, NN);
  ep1<<<(NN + 3) / 4, 256, 0, stream>>>(mx1, xn0, hb1, ai1, aj1, s1i, s1j);
  k_agg1<<<(NN + 3) / 4, 256, 0, stream>>>(rowptr, col, mx1, s1i, s1j, hact, xn1);
  kgemm<256, 128, 1, 4><<<(NN + 63) / 64, 256, 0, stream>>>(hact, W2, mx2, NN);
  ep2<<<(NN + 3) / 4, 256, 0, stream>>>(mx2, xn1, hb2, ai2, aj2, s1i, s1j);
  k_agg2<<<(NN + 3) / 4, 256, 0, stream>>>(rowptr, col, mx2, s1i, s1j, out);
}

// Round 3
// 578.699 us; speedup vs baseline: 1.4886x; 1.1488x over previous
//
#include <hip/hip_runtime.h>
#include <hip/hip_fp16.h>

#define NN 50000
#define NER 800000
#define NE 850000
#define MAXN 0.996f
#define MINNRM 1e-15f

__device__ __forceinline__ float wsum(float v){
#pragma unroll
  for (int m = 32; m >= 1; m >>= 1) v += __shfl_xor(v, m, 64);
  return v;
}
__device__ __forceinline__ float wmax(float v){
#pragma unroll
  for (int m = 32; m >= 1; m >>= 1) v = fmaxf(v, __shfl_xor(v, m, 64));
  return v;
}
__device__ __forceinline__ float artanh_c(float t){
  t = fminf(t, 1.0f - 1e-7f);
  return 0.5f * (log1pf(t) - log1pf(-t));
}
__device__ __forceinline__ float lrelu(float t, float s){ return t >= 0.f ? t : s * t; }

// ---- bias: hb = proj(expmap0(b)), plus |hb|^2 at hb[L] ----
__global__ void kbias(const float* __restrict__ b, int L, float* __restrict__ hb){
  __shared__ float red[256];
  int t = threadIdx.x;
  float v = (t < L) ? b[t] : 0.f;
  red[t] = v * v; __syncthreads();
  for (int s = 128; s; s >>= 1){ if (t < s) red[t] += red[t + s]; __syncthreads(); }
  float n  = fmaxf(sqrtf(red[0]), MINNRM);
  float un = tanhf(n);
  float nn = un;
  float f  = un / n;
  if (un > MAXN){ f = MAXN / n; nn = MAXN; }
  if (t < L) hb[t] = v * f;
  if (t == 0) hb[L] = nn * nn;
}

// ---- CSR build ----
__global__ void khist(const int* __restrict__ ei, int* __restrict__ cnt){
  int e = blockIdx.x * blockDim.x + threadIdx.x;
  if (e >= NE) return;
  int s = (e < NER) ? ei[e] : (e - NER);
  atomicAdd(&cnt[s], 1);
}

__global__ void kscan(int* __restrict__ cnt_cursor, int* __restrict__ rowptr){
  __shared__ int sh[1024];
  int t = threadIdx.x;
  const int CH = (NN + 1023) / 1024;
  int lo = t * CH, hi = min(lo + CH, NN);
  int s = 0;
  for (int i = lo; i < hi; i++) s += cnt_cursor[i];
  sh[t] = s; __syncthreads();
  for (int d = 1; d < 1024; d <<= 1){
    int v = (t >= d) ? sh[t - d] : 0;
    __syncthreads();
    sh[t] += v;
    __syncthreads();
  }
  int base = (t > 0) ? sh[t - 1] : 0;
  for (int i = lo; i < hi; i++){
    int c = cnt_cursor[i];
    rowptr[i] = base;
    cnt_cursor[i] = base;   // becomes fill cursor
    base += c;
  }
  if (t == 1023) rowptr[NN] = sh[1023];
}

__global__ void kfill(const int* __restrict__ ei, int* __restrict__ cursor, int* __restrict__ col){
  int e = blockIdx.x * blockDim.x + threadIdx.x;
  if (e >= NE) return;
  int s, d;
  if (e < NER){ s = ei[e]; d = ei[NER + e]; }
  else { s = e - NER; d = s; }
  int pos = atomicAdd(&cursor[s], 1);
  col[pos] = d;
}

// ---- G0 fused: h0 = proj(expmap0(x @ Wl^T + bl)) + xn0 ----
__global__ __launch_bounds__(256) void k_g0(const float* __restrict__ x, const float* __restrict__ Wl,
                                            const float* __restrict__ bl, float* __restrict__ h0,
                                            float* __restrict__ xn0){
  __shared__ float As[32][260];
  __shared__ float Bs[32][68];
  int tid = threadIdx.x;
  int wave = tid >> 6, lane = tid & 63;
  int lr = lane >> 3, lc = lane & 7;
  int row0 = blockIdx.x * 256;
  int r0 = wave * 64 + lr * 8;
  int c0 = lc * 8;
  float acc[8][8] = {};
  for (int k0 = 0; k0 < 128; k0 += 32){
    __syncthreads();
    for (int f = tid; f < 256 * 8; f += 256){
      int m = f >> 3, ko = (f & 7) * 4;
      int row = row0 + m;
      float4 v = make_float4(0.f,0.f,0.f,0.f);
      if (row < NN) v = *(const float4*)(x + (size_t)row * 128 + k0 + ko);
      As[ko+0][m]=v.x; As[ko+1][m]=v.y; As[ko+2][m]=v.z; As[ko+3][m]=v.w;
    }
    for (int f = tid; f < 64 * 8; f += 256){
      int n = f >> 3, ko = (f & 7) * 4;
      float4 v = *(const float4*)(Wl + (size_t)n * 128 + k0 + ko);
      Bs[ko+0][n]=v.x; Bs[ko+1][n]=v.y; Bs[ko+2][n]=v.z; Bs[ko+3][n]=v.w;
    }
    __syncthreads();
#pragma unroll 4
    for (int k = 0; k < 32; k++){
      float a[8], b[8];
      *(float4*)&a[0] = *(const float4*)&As[k][r0];
      *(float4*)&a[4] = *(const float4*)&As[k][r0+4];
      *(float4*)&b[0] = *(const float4*)&Bs[k][c0];
      *(float4*)&b[4] = *(const float4*)&Bs[k][c0+4];
#pragma unroll
      for (int i = 0; i < 8; i++)
#pragma unroll
        for (int j = 0; j < 8; j++)
          acc[i][j] = fmaf(a[i], b[j], acc[i][j]);
    }
  }
  float bb[8];
  *(float4*)&bb[0] = *(const float4*)(bl + c0);
  *(float4*)&bb[4] = *(const float4*)(bl + c0 + 4);
#pragma unroll
  for (int i = 0; i < 8; i++){
    float rs = 0.f;
#pragma unroll
    for (int j = 0; j < 8; j++){ acc[i][j] += bb[j]; rs = fmaf(acc[i][j], acc[i][j], rs); }
    rs += __shfl_xor(rs, 1, 64);
    rs += __shfl_xor(rs, 2, 64);
    rs += __shfl_xor(rs, 4, 64);
    float n  = fmaxf(sqrtf(rs), MINNRM);
    float un = tanhf(n);
    float f, nm;
    if (un > MAXN){ f = MAXN / n; nm = MAXN; } else { f = un / n; nm = un; }
    int row = row0 + r0 + i;
    if (row < NN){
#pragma unroll
      for (int j = 0; j < 8; j++) acc[i][j] *= f;
      float* cp = h0 + (size_t)row * 64 + c0;
      *(float4*)cp     = *(float4*)&acc[i][0];
      *(float4*)(cp+4) = *(float4*)&acc[i][4];
      if (lc == 0) xn0[row] = nm;
    }
  }
}

// ---- generic raw GEMM: C[M x N] = A[M x K] @ B[N x K]^T ----
template<int N, int K, int WR, int WC>
__global__ __launch_bounds__(256) void kgemm(const float* __restrict__ A, const float* __restrict__ B,
                                             float* __restrict__ C, int M){
  constexpr int BM = WR * 64;
  __shared__ float As[32][BM + 4];
  __shared__ float Bs[32][N + 4];
  int tid = threadIdx.x;
  int wave = tid >> 6, lane = tid & 63;
  int wr = wave / WC, wc = wave % WC;
  int lr = lane >> 3, lc = lane & 7;
  int row0 = blockIdx.x * BM;
  int r0 = wr * 64 + lr * 8;
  int c0 = wc * 64 + lc * 8;
  float acc[8][8] = {};
  for (int k0 = 0; k0 < K; k0 += 32){
    __syncthreads();
    for (int f = tid; f < BM * 8; f += 256){
      int m = f >> 3, ko = (f & 7) * 4;
      int row = row0 + m;
      float4 v = make_float4(0.f,0.f,0.f,0.f);
      if (row < M) v = *(const float4*)(A + (size_t)row * K + k0 + ko);
      As[ko+0][m]=v.x; As[ko+1][m]=v.y; As[ko+2][m]=v.z; As[ko+3][m]=v.w;
    }
    for (int f = tid; f < N * 8; f += 256){
      int n = f >> 3, ko = (f & 7) * 4;
      float4 v = *(const float4*)(B + (size_t)n * K + k0 + ko);
      Bs[ko+0][n]=v.x; Bs[ko+1][n]=v.y; Bs[ko+2][n]=v.z; Bs[ko+3][n]=v.w;
    }
    __syncthreads();
#pragma unroll 4
    for (int k = 0; k < 32; k++){
      float a[8], b[8];
      *(float4*)&a[0] = *(const float4*)&As[k][r0];
      *(float4*)&a[4] = *(const float4*)&As[k][r0+4];
      *(float4*)&b[0] = *(const float4*)&Bs[k][c0];
      *(float4*)&b[4] = *(const float4*)&Bs[k][c0+4];
#pragma unroll
      for (int i = 0; i < 8; i++)
#pragma unroll
        for (int j = 0; j < 8; j++)
          acc[i][j] = fmaf(a[i], b[j], acc[i][j]);
    }
  }
#pragma unroll
  for (int i = 0; i < 8; i++){
    int row = row0 + r0 + i;
    if (row < M){
      float* cp = C + (size_t)row * N + c0;
      *(float4*)cp     = *(float4*)&acc[i][0];
      *(float4*)(cp+4) = *(float4*)&acc[i][4];
    }
  }
}

// ---- ep1: mx1 -> ht1 (fp16) + s1 dots ----
__global__ __launch_bounds__(256) void ep1(const float* __restrict__ mx1, const float* __restrict__ xn0,
    const float* __restrict__ hb, const float* __restrict__ ai, const float* __restrict__ aj,
    __half* __restrict__ ht1, float* __restrict__ s1i, float* __restrict__ s1j){
  int wave = threadIdx.x >> 6, lane = threadIdx.x & 63;
  int row = blockIdx.x * 4 + wave;
  if (row >= NN) return;
  size_t base = (size_t)row * 128;
  float a0 = mx1[base + lane], a1 = mx1[base + 64 + lane];
  float xn = fmaxf(xn0[row], MINNRM);
  float r_art = artanh_c(xn);
  float mxn = fmaxf(sqrtf(wsum(a0 * a0 + a1 * a1)), MINNRM);
  float tn  = tanhf(mxn / xn * r_art);
  float sc  = tn / mxn;
  float r0 = a0 * sc, r1 = a1 * sc;
  float rn = tn;
  if (rn > MAXN){ float f = MAXN / rn; r0 *= f; r1 *= f; rn = MAXN; }
  float a2 = rn * rn;
  float hv0 = hb[lane], hv1 = hb[lane + 64];
  float b2 = hb[128];
  float ab = wsum(r0 * hv0 + r1 * hv1);
  float co1 = 1.f + 2.f * ab + b2;
  float co2 = 1.f - a2;
  float den = fmaxf(1.f + 2.f * ab + a2 * b2, MINNRM);
  float h_0 = (co1 * r0 + co2 * hv0) / den;
  float h_1 = (co1 * r1 + co2 * hv1) / den;
  float hn = fmaxf(sqrtf(wsum(h_0 * h_0 + h_1 * h_1)), MINNRM);
  if (hn > MAXN){ float f = MAXN / hn; h_0 *= f; h_1 *= f; hn = MAXN; }
  float lf = artanh_c(hn) / hn;
  float t0 = h_0 * lf, t1 = h_1 * lf;
  ht1[base + lane]      = __float2half(t0);
  ht1[base + 64 + lane] = __float2half(t1);
  float pi0 = t0 * ai[lane], pi1 = t1 * ai[lane + 64];
  float pj0 = t0 * aj[lane], pj1 = t1 * aj[lane + 64];
#pragma unroll
  for (int m = 16; m >= 1; m >>= 1){
    pi0 += __shfl_xor(pi0, m, 64); pi1 += __shfl_xor(pi1, m, 64);
    pj0 += __shfl_xor(pj0, m, 64); pj1 += __shfl_xor(pj1, m, 64);
  }
  if (lane == 0){ s1i[row*4+0]=pi0; s1i[row*4+2]=pi1; s1j[row*4+0]=pj0; s1j[row*4+2]=pj1; }
  if (lane == 32){ s1i[row*4+1]=pi0; s1i[row*4+3]=pi1; s1j[row*4+1]=pj0; s1j[row*4+3]=pj1; }
}

// ---- agg1: flash softmax-aggregate + hyp_act -> hact (fp32), xn1 ----
__global__ __launch_bounds__(256) void k_agg1(const int* __restrict__ rowptr, const int* __restrict__ col,
    const __half* __restrict__ ht1, const float* __restrict__ s1i, const float* __restrict__ s1j,
    float* __restrict__ hact, float* __restrict__ xn1){
  __shared__ float wlds[4][64][4];
  int wave = threadIdx.x >> 6, lane = threadIdx.x & 63;
  int n = blockIdx.x * 4 + wave;
  if (n >= NN) return;
  int p0 = rowptr[n], p1 = rowptr[n + 1];
  float4 si = *(const float4*)(s1i + (size_t)n * 4);
  int h = lane >> 4;
  float m0=-1e30f,m1=-1e30f,m2=-1e30f,m3=-1e30f;
  float s0=0.f,s1=0.f,s2=0.f,s3=0.f;
  float acc0=0.f, acc1=0.f;
  for (int base = p0; base < p1; base += 64){
    int myE = base + lane;
    int d = 0;
    float a0=-1e30f,a1=-1e30f,a2=-1e30f,a3=-1e30f;
    if (myE < p1){
      d = col[myE];
      float4 sj = *(const float4*)(s1j + (size_t)d * 4);
      a0 = lrelu(si.x + sj.x, 0.2f);
      a1 = lrelu(si.y + sj.y, 0.2f);
      a2 = lrelu(si.z + sj.z, 0.2f);
      a3 = lrelu(si.w + sj.w, 0.2f);
    }
    float nm0 = fmaxf(m0, wmax(a0)), nm1 = fmaxf(m1, wmax(a1));
    float nm2 = fmaxf(m2, wmax(a2)), nm3 = fmaxf(m3, wmax(a3));
    float r0 = __expf(m0 - nm0), r1 = __expf(m1 - nm1);
    float r2 = __expf(m2 - nm2), r3 = __expf(m3 - nm3);
    float w0 = __expf(a0 - nm0), w1 = __expf(a1 - nm1);
    float w2 = __expf(a2 - nm2), w3 = __expf(a3 - nm3);
    s0 = s0 * r0 + wsum(w0); s1 = s1 * r1 + wsum(w1);
    s2 = s2 * r2 + wsum(w2); s3 = s3 * r3 + wsum(w3);
    m0 = nm0; m1 = nm1; m2 = nm2; m3 = nm3;
    float rsel = (h==0)?r0:(h==1)?r1:(h==2)?r2:r3;
    acc0 *= rsel; acc1 *= rsel;
    *(float4*)&wlds[wave][lane][0] = make_float4(w0, w1, w2, w3);
    __builtin_amdgcn_wave_barrier();
    int cnt = min(p1 - base, 64);
    int q = 0;
    for (; q + 1 < cnt; q += 2){
      int dA = __builtin_amdgcn_readlane(d, q);
      int dB = __builtin_amdgcn_readlane(d, q + 1);
      float WA = wlds[wave][q][h];
      float WB = wlds[wave][q + 1][h];
      float2 vA = __half22float2(*(const __half2*)(ht1 + (size_t)dA * 128 + 2 * lane));
      float2 vB = __half22float2(*(const __half2*)(ht1 + (size_t)dB * 128 + 2 * lane));
      acc0 += WA * vA.x + WB * vB.x;
      acc1 += WA * vA.y + WB * vB.y;
    }
    if (q < cnt){
      int dA = __builtin_amdgcn_readlane(d, q);
      float WA = wlds[wave][q][h];
      float2 vA = __half22float2(*(const __half2*)(ht1 + (size_t)dA * 128 + 2 * lane));
      acc0 += WA * vA.x;
      acc1 += WA * vA.y;
    }
    __builtin_amdgcn_wave_barrier();
  }
  float ssel = (h==0)?s0:(h==1)?s1:(h==2)?s2:s3;
  float rinv = 1.f / (ssel + 1e-16f);
  acc0 *= rinv; acc1 *= rinv;
  // proj(expmap0(acc)) -> logmap0 -> lrelu(0.01) -> proj(expmap0)
  float nn = fmaxf(sqrtf(wsum(acc0*acc0 + acc1*acc1)), MINNRM);
  float un = tanhf(nn);
  float f  = un / nn; float uN = un;
  if (un > MAXN){ f = MAXN / nn; uN = MAXN; }
  float lg = artanh_c(uN) / fmaxf(uN, MINNRM);
  float t0 = lrelu(acc0 * f * lg, 0.01f);
  float t1 = lrelu(acc1 * f * lg, 0.01f);
  float nn2 = fmaxf(sqrtf(wsum(t0*t0 + t1*t1)), MINNRM);
  float un2 = tanhf(nn2);
  float f2, nm2v;
  if (un2 > MAXN){ f2 = MAXN / nn2; nm2v = MAXN; } else { f2 = un2 / nn2; nm2v = un2; }
  float2 o2; o2.x = t0 * f2; o2.y = t1 * f2;
  *(float2*)(hact + (size_t)n * 128 + 2 * lane) = o2;
  if (lane == 0) xn1[n] = nm2v;
}

// ---- ep2: mx2 -> ht2 (fp16, [n][feat][head] layout) + s2 dots ----
__global__ __launch_bounds__(256) void ep2(const float* __restrict__ mx2, const float* __restrict__ xn1,
    const float* __restrict__ hb, const float* __restrict__ ai, const float* __restrict__ aj,
    __half* __restrict__ ht2, float* __restrict__ s2i, float* __restrict__ s2j){
  int wave = threadIdx.x >> 6, lane = threadIdx.x & 63;
  int row = blockIdx.x * 4 + wave;
  if (row >= NN) return;
  size_t base = (size_t)row * 256;
  float v0 = mx2[base + lane], v1 = mx2[base + 64 + lane];
  float v2 = mx2[base + 128 + lane], v3 = mx2[base + 192 + lane];
  float xn = fmaxf(xn1[row], MINNRM);
  float r_art = artanh_c(xn);
  float mxn = fmaxf(sqrtf(wsum(v0*v0 + v1*v1 + v2*v2 + v3*v3)), MINNRM);
  float tn = tanhf(mxn / xn * r_art);
  float sc = tn / mxn;
  float res0 = v0*sc, res1 = v1*sc, res2 = v2*sc, res3 = v3*sc;
  float rn = tn;
  if (rn > MAXN){ float f = MAXN / rn; res0*=f; res1*=f; res2*=f; res3*=f; rn = MAXN; }
  float a2 = rn * rn;
  float hb0 = hb[lane], hb1v = hb[64 + lane], hb2v = hb[128 + lane], hb3 = hb[192 + lane];
  float b2 = hb[256];
  float ab = wsum(res0*hb0 + res1*hb1v + res2*hb2v + res3*hb3);
  float co1 = 1.f + 2.f * ab + b2;
  float co2 = 1.f - a2;
  float den = fmaxf(1.f + 2.f * ab + a2 * b2, MINNRM);
  float h0v = (co1*res0 + co2*hb0) / den;
  float h1v = (co1*res1 + co2*hb1v) / den;
  float h2v = (co1*res2 + co2*hb2v) / den;
  float h3v = (co1*res3 + co2*hb3) / den;
  float hn = fmaxf(sqrtf(wsum(h0v*h0v + h1v*h1v + h2v*h2v + h3v*h3v)), MINNRM);
  if (hn > MAXN){ float f = MAXN / hn; h0v*=f; h1v*=f; h2v*=f; h3v*=f; hn = MAXN; }
  float lf = artanh_c(hn) / hn;
  float t0 = h0v*lf, t1 = h1v*lf, t2 = h2v*lf, t3 = h3v*lf;
  union { __half2 hh[2]; float2 ff; } u;
  u.hh[0] = __floats2half2_rn(t0, t1);
  u.hh[1] = __floats2half2_rn(t2, t3);
  *(float2*)(ht2 + base + 4 * lane) = u.ff;
  float pi0 = wsum(t0 * ai[lane]);
  float pi1 = wsum(t1 * ai[64 + lane]);
  float pi2 = wsum(t2 * ai[128 + lane]);
  float pi3 = wsum(t3 * ai[192 + lane]);
  float pj0 = wsum(t0 * aj[lane]);
  float pj1 = wsum(t1 * aj[64 + lane]);
  float pj2 = wsum(t2 * aj[128 + lane]);
  float pj3 = wsum(t3 * aj[192 + lane]);
  if (lane == 0){
    s2i[row*4+0]=pi0; s2i[row*4+1]=pi1; s2i[row*4+2]=pi2; s2i[row*4+3]=pi3;
    s2j[row*4+0]=pj0; s2j[row*4+1]=pj1; s2j[row*4+2]=pj2; s2j[row*4+3]=pj3;
  }
}

// ---- agg2: flash softmax-aggregate (4 heads, mean) + hyp_act + logmap0 -> out ----
__global__ __launch_bounds__(256) void k_agg2(const int* __restrict__ rowptr, const int* __restrict__ col,
    const __half* __restrict__ ht2, const float* __restrict__ s2i, const float* __restrict__ s2j,
    float* __restrict__ out){
  __shared__ float wlds[4][64][4];
  int wave = threadIdx.x >> 6, lane = threadIdx.x & 63;
  int n = blockIdx.x * 4 + wave;
  if (n >= NN) return;
  int p0 = rowptr[n], p1 = rowptr[n + 1];
  float4 si = *(const float4*)(s2i + (size_t)n * 4);
  float m0=-1e30f,m1=-1e30f,m2=-1e30f,m3=-1e30f;
  float s0=0.f,s1=0.f,s2=0.f,s3=0.f;
  float a0=0.f,a1=0.f,a2=0.f,a3=0.f;
  for (int base = p0; base < p1; base += 64){
    int myE = base + lane;
    int d = 0;
    float q0=-1e30f,q1=-1e30f,q2=-1e30f,q3=-1e30f;
    if (myE < p1){
      d = col[myE];
      float4 sj = *(const float4*)(s2j + (size_t)d * 4);
      q0 = lrelu(si.x + sj.x, 0.2f);
      q1 = lrelu(si.y + sj.y, 0.2f);
      q2 = lrelu(si.z + sj.z, 0.2f);
      q3 = lrelu(si.w + sj.w, 0.2f);
    }
    float nm0 = fmaxf(m0, wmax(q0)), nm1 = fmaxf(m1, wmax(q1));
    float nm2 = fmaxf(m2, wmax(q2)), nm3 = fmaxf(m3, wmax(q3));
    float r0 = __expf(m0 - nm0), r1 = __expf(m1 - nm1);
    float r2 = __expf(m2 - nm2), r3 = __expf(m3 - nm3);
    float w0 = __expf(q0 - nm0), w1 = __expf(q1 - nm1);
    float w2 = __expf(q2 - nm2), w3 = __expf(q3 - nm3);
    s0 = s0 * r0 + wsum(w0); s1 = s1 * r1 + wsum(w1);
    s2 = s2 * r2 + wsum(w2); s3 = s3 * r3 + wsum(w3);
    m0 = nm0; m1 = nm1; m2 = nm2; m3 = nm3;
    a0 *= r0; a1 *= r1; a2 *= r2; a3 *= r3;
    *(float4*)&wlds[wave][lane][0] = make_float4(w0, w1, w2, w3);
    __builtin_amdgcn_wave_barrier();
    int cnt = min(p1 - base, 64);
    int q = 0;
    for (; q + 1 < cnt; q += 2){
      int dA = __builtin_amdgcn_readlane(d, q);
      int dB = __builtin_amdgcn_readlane(d, q + 1);
      float4 WA = *(const float4*)&wlds[wave][q][0];
      float4 WB = *(const float4*)&wlds[wave][q + 1][0];
      union { float2 ff; __half2 hh[2]; } uA, uB;
      uA.ff = *(const float2*)(ht2 + (size_t)dA * 256 + 4 * lane);
      uB.ff = *(const float2*)(ht2 + (size_t)dB * 256 + 4 * lane);
      float2 vA01 = __half22float2(uA.hh[0]), vA23 = __half22float2(uA.hh[1]);
      float2 vB01 = __half22float2(uB.hh[0]), vB23 = __half22float2(uB.hh[1]);
      a0 += WA.x * vA01.x + WB.x * vB01.x;
      a1 += WA.y * vA01.y + WB.y * vB01.y;
      a2 += WA.z * vA23.x + WB.z * vB23.x;
      a3 += WA.w * vA23.y + WB.w * vB23.y;
    }
    if (q < cnt){
      int dA = __builtin_amdgcn_readlane(d, q);
      float4 WA = *(const float4*)&wlds[wave][q][0];
      union { float2 ff; __half2 hh[2]; } uA;
      uA.ff = *(const float2*)(ht2 + (size_t)dA * 256 + 4 * lane);
      float2 vA01 = __half22float2(uA.hh[0]), vA23 = __half22float2(uA.hh[1]);
      a0 += WA.x * vA01.x;
      a1 += WA.y * vA01.y;
      a2 += WA.z * vA23.x;
      a3 += WA.w * vA23.y;
    }
    __builtin_amdgcn_wave_barrier();
  }
  a0 /= (s0 + 1e-16f); a1 /= (s1 + 1e-16f);
  a2 /= (s2 + 1e-16f); a3 /= (s3 + 1e-16f);
  float mean = 0.25f * (a0 + a1 + a2 + a3);
  float nn = fmaxf(sqrtf(wsum(mean * mean)), MINNRM);
  float un = tanhf(nn);
  float f = un / nn; float uN = un;
  if (un > MAXN){ f = MAXN / nn; uN = MAXN; }
  float lg = artanh_c(uN) / fmaxf(uN, MINNRM);
  float t = lrelu(mean * f * lg, 0.01f);
  float nn2 = fmaxf(sqrtf(wsum(t * t)), MINNRM);
  float un2 = tanhf(nn2);
  float f2 = (un2 > MAXN) ? (MAXN / nn2) : (un2 / nn2);
  float uN2 = fminf(un2, MAXN);
  float lg2 = artanh_c(uN2) / fmaxf(uN2, MINNRM);
  out[(size_t)n * 64 + lane] = t * f2 * lg2;
}

extern "C" void kernel_launch(void* const* d_in, const int* in_sizes, int n_in,
                              void* d_out, int out_size, void* d_ws, size_t ws_size,
                              hipStream_t stream){
  const float* x   = (const float*)d_in[0];
  const float* Wl  = (const float*)d_in[1];
  const float* bl  = (const float*)d_in[2];
  const float* W1  = (const float*)d_in[3];
  const float* b1  = (const float*)d_in[4];
  const float* ai1 = (const float*)d_in[5];
  const float* aj1 = (const float*)d_in[6];
  const float* W2  = (const float*)d_in[7];
  const float* b2  = (const float*)d_in[8];
  const float* ai2 = (const float*)d_in[9];
  const float* aj2 = (const float*)d_in[10];
  const int*   ei  = (const int*)d_in[11];
  float* out = (float*)d_out;
  float* ws  = (float*)d_ws;

  // slab layout (float units):
  //  h0    [0, 3.2M)          dead after kgemm1
  //  mx1   [3.2M, 9.6M)       dead after ep1
  //  ht1h  [9.6M, 12.8M)      fp16, dead after agg1
  //  hact  [12.8M, 19.2M)     dead after kgemm2
  //  mx2   [0, 12.8M)         (h0,mx1,ht1h dead) dead after ep2
  //  ht2h  [12.8M, 19.2M)     fp16, aliases dead hact
  float* h0     = ws;
  float* mx1    = ws + 3200000;
  __half* ht1h  = (__half*)(ws + 9600000);
  float* hact   = ws + 12800000;
  float* mx2    = ws;
  __half* ht2h  = (__half*)(ws + 12800000);
  float* xn0    = ws + 19200000;
  float* xn1    = ws + 19250000;
  float* s1i    = ws + 19300000;  // = s2i (s1 dead after agg1)
  float* s1j    = ws + 19500000;  // = s2j
  float* hb1    = ws + 19700000;
  float* hb2    = ws + 19700132;
  int* rowptr   = (int*)(ws + 19700392);  // NN+1
  int* cnt      = rowptr + NN + 1;        // NN
  int* col      = cnt + NN;               // NE

  hipMemsetAsync(cnt, 0, NN * sizeof(int), stream);
  kbias<<<1, 256, 0, stream>>>(b1, 128, hb1);
  kbias<<<1, 256, 0, stream>>>(b2, 256, hb2);
  khist<<<(NE + 255) / 256, 256, 0, stream>>>(ei, cnt);
  kscan<<<1, 1024, 0, stream>>>(cnt, rowptr);
  kfill<<<(NE + 255) / 256, 256, 0, stream>>>(ei, cnt, col);
  k_g0<<<(NN + 255) / 256, 256, 0, stream>>>(x, Wl, bl, h0, xn0);
  kgemm<128, 64, 2, 2><<<(NN + 127) / 128, 256, 0, stream>>>(h0, W1, mx1, NN);
  ep1<<<(NN + 3) / 4, 256, 0, stream>>>(mx1, xn0, hb1, ai1, aj1, ht1h, s1i, s1j);
  k_agg1<<<(NN + 3) / 4, 256, 0, stream>>>(rowptr, col, ht1h, s1i, s1j, hact, xn1);
  kgemm<256, 128, 1, 4><<<(NN + 63) / 64, 256, 0, stream>>>(hact, W2, mx2, NN);
  ep2<<<(NN + 3) / 4, 256, 0, stream>>>(mx2, xn1, hb2, ai2, aj2, ht2h, s1i, s1j);
  k_agg2<<<(NN + 3) / 4, 256, 0, stream>>>(rowptr, col, ht2h, s1i, s1j, out);
}

// Round 4
// 472.860 us; speedup vs baseline: 1.8218x; 1.2238x over previous
//
#include <hip/hip_runtime.h>
#include <hip/hip_fp16.h>

#define NN 50000
#define NER 800000
#define NE 850000
#define MAXN 0.996f
#define MINNRM 1e-15f
#define SCAN_B 512
#define NBLK ((NN + SCAN_B - 1) / SCAN_B)   // 98

__device__ __forceinline__ float wsum(float v){
#pragma unroll
  for (int m = 32; m >= 1; m >>= 1) v += __shfl_xor(v, m, 64);
  return v;
}
__device__ __forceinline__ float wmax(float v){
#pragma unroll
  for (int m = 32; m >= 1; m >>= 1) v = fmaxf(v, __shfl_xor(v, m, 64));
  return v;
}
__device__ __forceinline__ float artanh_c(float t){
  t = fminf(t, 1.0f - 1e-7f);
  return 0.5f * (log1pf(t) - log1pf(-t));
}
__device__ __forceinline__ float lrelu(float t, float s){ return t >= 0.f ? t : s * t; }

// ---- bias: hb = proj(expmap0(b)), plus |hb|^2 at hb[L] ----
__global__ void kbias(const float* __restrict__ b, int L, float* __restrict__ hb){
  __shared__ float red[256];
  int t = threadIdx.x;
  float v = (t < L) ? b[t] : 0.f;
  red[t] = v * v; __syncthreads();
  for (int s = 128; s; s >>= 1){ if (t < s) red[t] += red[t + s]; __syncthreads(); }
  float n  = fmaxf(sqrtf(red[0]), MINNRM);
  float un = tanhf(n);
  float nn = un;
  float f  = un / n;
  if (un > MAXN){ f = MAXN / n; nn = MAXN; }
  if (t < L) hb[t] = v * f;
  if (t == 0) hb[L] = nn * nn;
}

// ---- CSR build ----
__global__ void khist(const int* __restrict__ ei, int* __restrict__ cnt){
  int e = blockIdx.x * blockDim.x + threadIdx.x;
  if (e >= NE) return;
  int s = (e < NER) ? ei[e] : (e - NER);
  atomicAdd(&cnt[s], 1);
}

// hierarchical scan: block-local inclusive scan + block sums
__global__ __launch_bounds__(SCAN_B) void kscan1(const int* __restrict__ cnt,
                                                 int* __restrict__ part, int* __restrict__ bsum){
  __shared__ int sh[SCAN_B];
  int t = threadIdx.x;
  int i = blockIdx.x * SCAN_B + t;
  int v = (i < NN) ? cnt[i] : 0;
  sh[t] = v; __syncthreads();
  for (int d = 1; d < SCAN_B; d <<= 1){
    int u = (t >= d) ? sh[t - d] : 0;
    __syncthreads();
    sh[t] += u;
    __syncthreads();
  }
  if (i < NN) part[i] = sh[t];
  if (t == SCAN_B - 1) bsum[blockIdx.x] = sh[t];
}

// scan the 98 block sums (single small block)
__global__ __launch_bounds__(128) void kscan2(int* __restrict__ bsum){
  __shared__ int sh[128];
  int t = threadIdx.x;
  int v = (t < NBLK) ? bsum[t] : 0;
  sh[t] = v; __syncthreads();
  for (int d = 1; d < 128; d <<= 1){
    int u = (t >= d) ? sh[t - d] : 0;
    __syncthreads();
    sh[t] += u;
    __syncthreads();
  }
  if (t < NBLK) bsum[t] = sh[t];
}

// exclusive global prefix -> rowptr + cursor (cursor aliases cnt; same-thread RMW is safe)
__global__ __launch_bounds__(SCAN_B) void kscan3(const int* __restrict__ part, const int* __restrict__ bsum,
                                                 int* __restrict__ rowptr, int* __restrict__ cursor){
  int t = threadIdx.x;
  int i = blockIdx.x * SCAN_B + t;
  if (i < NN){
    int base = blockIdx.x ? bsum[blockIdx.x - 1] : 0;
    int excl = base + part[i] - cursor[i];   // cursor==cnt here (original counts)
    rowptr[i] = excl;
    cursor[i] = excl;
  }
  if (i == 0) rowptr[NN] = bsum[NBLK - 1];
}

__global__ void kfill(const int* __restrict__ ei, int* __restrict__ cursor, int* __restrict__ col){
  int e = blockIdx.x * blockDim.x + threadIdx.x;
  if (e >= NE) return;
  int s, d;
  if (e < NER){ s = ei[e]; d = ei[NER + e]; }
  else { s = e - NER; d = s; }
  int pos = atomicAdd(&cursor[s], 1);
  col[pos] = d;
}

// ---- G0 fused: h0 = proj(expmap0(x @ Wl^T + bl)) + xn0 ----
__global__ __launch_bounds__(256) void k_g0(const float* __restrict__ x, const float* __restrict__ Wl,
                                            const float* __restrict__ bl, float* __restrict__ h0,
                                            float* __restrict__ xn0){
  __shared__ float As[32][260];
  __shared__ float Bs[32][68];
  int tid = threadIdx.x;
  int wave = tid >> 6, lane = tid & 63;
  int lr = lane >> 3, lc = lane & 7;
  int row0 = blockIdx.x * 256;
  int r0 = wave * 64 + lr * 8;
  int c0 = lc * 8;
  float acc[8][8] = {};
  for (int k0 = 0; k0 < 128; k0 += 32){
    __syncthreads();
    for (int f = tid; f < 256 * 8; f += 256){
      int m = f >> 3, ko = (f & 7) * 4;
      int row = row0 + m;
      float4 v = make_float4(0.f,0.f,0.f,0.f);
      if (row < NN) v = *(const float4*)(x + (size_t)row * 128 + k0 + ko);
      As[ko+0][m]=v.x; As[ko+1][m]=v.y; As[ko+2][m]=v.z; As[ko+3][m]=v.w;
    }
    for (int f = tid; f < 64 * 8; f += 256){
      int n = f >> 3, ko = (f & 7) * 4;
      float4 v = *(const float4*)(Wl + (size_t)n * 128 + k0 + ko);
      Bs[ko+0][n]=v.x; Bs[ko+1][n]=v.y; Bs[ko+2][n]=v.z; Bs[ko+3][n]=v.w;
    }
    __syncthreads();
#pragma unroll 4
    for (int k = 0; k < 32; k++){
      float a[8], b[8];
      *(float4*)&a[0] = *(const float4*)&As[k][r0];
      *(float4*)&a[4] = *(const float4*)&As[k][r0+4];
      *(float4*)&b[0] = *(const float4*)&Bs[k][c0];
      *(float4*)&b[4] = *(const float4*)&Bs[k][c0+4];
#pragma unroll
      for (int i = 0; i < 8; i++)
#pragma unroll
        for (int j = 0; j < 8; j++)
          acc[i][j] = fmaf(a[i], b[j], acc[i][j]);
    }
  }
  float bb[8];
  *(float4*)&bb[0] = *(const float4*)(bl + c0);
  *(float4*)&bb[4] = *(const float4*)(bl + c0 + 4);
#pragma unroll
  for (int i = 0; i < 8; i++){
    float rs = 0.f;
#pragma unroll
    for (int j = 0; j < 8; j++){ acc[i][j] += bb[j]; rs = fmaf(acc[i][j], acc[i][j], rs); }
    rs += __shfl_xor(rs, 1, 64);
    rs += __shfl_xor(rs, 2, 64);
    rs += __shfl_xor(rs, 4, 64);
    float n  = fmaxf(sqrtf(rs), MINNRM);
    float un = tanhf(n);
    float f, nm;
    if (un > MAXN){ f = MAXN / n; nm = MAXN; } else { f = un / n; nm = un; }
    int row = row0 + r0 + i;
    if (row < NN){
#pragma unroll
      for (int j = 0; j < 8; j++) acc[i][j] *= f;
      float* cp = h0 + (size_t)row * 64 + c0;
      *(float4*)cp     = *(float4*)&acc[i][0];
      *(float4*)(cp+4) = *(float4*)&acc[i][4];
      if (lc == 0) xn0[row] = nm;
    }
  }
}

// ---- generic raw GEMM: C[M x N] = A[M x K] @ B[N x K]^T ----
template<int N, int K, int WR, int WC>
__global__ __launch_bounds__(256) void kgemm(const float* __restrict__ A, const float* __restrict__ B,
                                             float* __restrict__ C, int M){
  constexpr int BM = WR * 64;
  __shared__ float As[32][BM + 4];
  __shared__ float Bs[32][N + 4];
  int tid = threadIdx.x;
  int wave = tid >> 6, lane = tid & 63;
  int wr = wave / WC, wc = wave % WC;
  int lr = lane >> 3, lc = lane & 7;
  int row0 = blockIdx.x * BM;
  int r0 = wr * 64 + lr * 8;
  int c0 = wc * 64 + lc * 8;
  float acc[8][8] = {};
  for (int k0 = 0; k0 < K; k0 += 32){
    __syncthreads();
    for (int f = tid; f < BM * 8; f += 256){
      int m = f >> 3, ko = (f & 7) * 4;
      int row = row0 + m;
      float4 v = make_float4(0.f,0.f,0.f,0.f);
      if (row < M) v = *(const float4*)(A + (size_t)row * K + k0 + ko);
      As[ko+0][m]=v.x; As[ko+1][m]=v.y; As[ko+2][m]=v.z; As[ko+3][m]=v.w;
    }
    for (int f = tid; f < N * 8; f += 256){
      int n = f >> 3, ko = (f & 7) * 4;
      float4 v = *(const float4*)(B + (size_t)n * K + k0 + ko);
      Bs[ko+0][n]=v.x; Bs[ko+1][n]=v.y; Bs[ko+2][n]=v.z; Bs[ko+3][n]=v.w;
    }
    __syncthreads();
#pragma unroll 4
    for (int k = 0; k < 32; k++){
      float a[8], b[8];
      *(float4*)&a[0] = *(const float4*)&As[k][r0];
      *(float4*)&a[4] = *(const float4*)&As[k][r0+4];
      *(float4*)&b[0] = *(const float4*)&Bs[k][c0];
      *(float4*)&b[4] = *(const float4*)&Bs[k][c0+4];
#pragma unroll
      for (int i = 0; i < 8; i++)
#pragma unroll
        for (int j = 0; j < 8; j++)
          acc[i][j] = fmaf(a[i], b[j], acc[i][j]);
    }
  }
#pragma unroll
  for (int i = 0; i < 8; i++){
    int row = row0 + r0 + i;
    if (row < M){
      float* cp = C + (size_t)row * N + c0;
      *(float4*)cp     = *(float4*)&acc[i][0];
      *(float4*)(cp+4) = *(float4*)&acc[i][4];
    }
  }
}

// ---- ep1: mx1 -> ht1 (fp16) + s1 dots ----
__global__ __launch_bounds__(256) void ep1(const float* __restrict__ mx1, const float* __restrict__ xn0,
    const float* __restrict__ hb, const float* __restrict__ ai, const float* __restrict__ aj,
    __half* __restrict__ ht1, float* __restrict__ s1i, float* __restrict__ s1j){
  int wave = threadIdx.x >> 6, lane = threadIdx.x & 63;
  int row = blockIdx.x * 4 + wave;
  if (row >= NN) return;
  size_t base = (size_t)row * 128;
  float a0 = mx1[base + lane], a1 = mx1[base + 64 + lane];
  float xn = fmaxf(xn0[row], MINNRM);
  float r_art = artanh_c(xn);
  float mxn = fmaxf(sqrtf(wsum(a0 * a0 + a1 * a1)), MINNRM);
  float tn  = tanhf(mxn / xn * r_art);
  float sc  = tn / mxn;
  float r0 = a0 * sc, r1 = a1 * sc;
  float rn = tn;
  if (rn > MAXN){ float f = MAXN / rn; r0 *= f; r1 *= f; rn = MAXN; }
  float a2 = rn * rn;
  float hv0 = hb[lane], hv1 = hb[lane + 64];
  float b2 = hb[128];
  float ab = wsum(r0 * hv0 + r1 * hv1);
  float co1 = 1.f + 2.f * ab + b2;
  float co2 = 1.f - a2;
  float den = fmaxf(1.f + 2.f * ab + a2 * b2, MINNRM);
  float h_0 = (co1 * r0 + co2 * hv0) / den;
  float h_1 = (co1 * r1 + co2 * hv1) / den;
  float hn = fmaxf(sqrtf(wsum(h_0 * h_0 + h_1 * h_1)), MINNRM);
  if (hn > MAXN){ float f = MAXN / hn; h_0 *= f; h_1 *= f; hn = MAXN; }
  float lf = artanh_c(hn) / hn;
  float t0 = h_0 * lf, t1 = h_1 * lf;
  ht1[base + lane]      = __float2half(t0);
  ht1[base + 64 + lane] = __float2half(t1);
  float pi0 = t0 * ai[lane], pi1 = t1 * ai[lane + 64];
  float pj0 = t0 * aj[lane], pj1 = t1 * aj[lane + 64];
#pragma unroll
  for (int m = 16; m >= 1; m >>= 1){
    pi0 += __shfl_xor(pi0, m, 64); pi1 += __shfl_xor(pi1, m, 64);
    pj0 += __shfl_xor(pj0, m, 64); pj1 += __shfl_xor(pj1, m, 64);
  }
  if (lane == 0){ s1i[row*4+0]=pi0; s1i[row*4+2]=pi1; s1j[row*4+0]=pj0; s1j[row*4+2]=pj1; }
  if (lane == 32){ s1i[row*4+1]=pi0; s1i[row*4+3]=pi1; s1j[row*4+1]=pj0; s1j[row*4+3]=pj1; }
}

// ---- agg1: flash softmax-aggregate + hyp_act -> hact (fp32), xn1 ----
__global__ __launch_bounds__(256) void k_agg1(const int* __restrict__ rowptr, const int* __restrict__ col,
    const __half* __restrict__ ht1, const float* __restrict__ s1i, const float* __restrict__ s1j,
    float* __restrict__ hact, float* __restrict__ xn1){
  __shared__ float wlds[4][64][4];
  int wave = threadIdx.x >> 6, lane = threadIdx.x & 63;
  int n = blockIdx.x * 4 + wave;
  if (n >= NN) return;
  int p0 = rowptr[n], p1 = rowptr[n + 1];
  float4 si = *(const float4*)(s1i + (size_t)n * 4);
  int h = lane >> 4;
  float m0=-1e30f,m1=-1e30f,m2=-1e30f,m3=-1e30f;
  float s0=0.f,s1=0.f,s2=0.f,s3=0.f;
  float acc0=0.f, acc1=0.f;
  for (int base = p0; base < p1; base += 64){
    int myE = base + lane;
    int d = 0;
    float a0=-1e30f,a1=-1e30f,a2=-1e30f,a3=-1e30f;
    if (myE < p1){
      d = col[myE];
      float4 sj = *(const float4*)(s1j + (size_t)d * 4);
      a0 = lrelu(si.x + sj.x, 0.2f);
      a1 = lrelu(si.y + sj.y, 0.2f);
      a2 = lrelu(si.z + sj.z, 0.2f);
      a3 = lrelu(si.w + sj.w, 0.2f);
    }
    float nm0 = fmaxf(m0, wmax(a0)), nm1 = fmaxf(m1, wmax(a1));
    float nm2 = fmaxf(m2, wmax(a2)), nm3 = fmaxf(m3, wmax(a3));
    float r0 = __expf(m0 - nm0), r1 = __expf(m1 - nm1);
    float r2 = __expf(m2 - nm2), r3 = __expf(m3 - nm3);
    float w0 = __expf(a0 - nm0), w1 = __expf(a1 - nm1);
    float w2 = __expf(a2 - nm2), w3 = __expf(a3 - nm3);
    s0 = s0 * r0 + wsum(w0); s1 = s1 * r1 + wsum(w1);
    s2 = s2 * r2 + wsum(w2); s3 = s3 * r3 + wsum(w3);
    m0 = nm0; m1 = nm1; m2 = nm2; m3 = nm3;
    float rsel = (h==0)?r0:(h==1)?r1:(h==2)?r2:r3;
    acc0 *= rsel; acc1 *= rsel;
    *(float4*)&wlds[wave][lane][0] = make_float4(w0, w1, w2, w3);
    __builtin_amdgcn_wave_barrier();
    int cnt = min(p1 - base, 64);
    int q = 0;
    for (; q + 1 < cnt; q += 2){
      int dA = __builtin_amdgcn_readlane(d, q);
      int dB = __builtin_amdgcn_readlane(d, q + 1);
      float WA = wlds[wave][q][h];
      float WB = wlds[wave][q + 1][h];
      float2 vA = __half22float2(*(const __half2*)(ht1 + (size_t)dA * 128 + 2 * lane));
      float2 vB = __half22float2(*(const __half2*)(ht1 + (size_t)dB * 128 + 2 * lane));
      acc0 += WA * vA.x + WB * vB.x;
      acc1 += WA * vA.y + WB * vB.y;
    }
    if (q < cnt){
      int dA = __builtin_amdgcn_readlane(d, q);
      float WA = wlds[wave][q][h];
      float2 vA = __half22float2(*(const __half2*)(ht1 + (size_t)dA * 128 + 2 * lane));
      acc0 += WA * vA.x;
      acc1 += WA * vA.y;
    }
    __builtin_amdgcn_wave_barrier();
  }
  float ssel = (h==0)?s0:(h==1)?s1:(h==2)?s2:s3;
  float rinv = 1.f / (ssel + 1e-16f);
  acc0 *= rinv; acc1 *= rinv;
  float nn = fmaxf(sqrtf(wsum(acc0*acc0 + acc1*acc1)), MINNRM);
  float un = tanhf(nn);
  float f  = un / nn; float uN = un;
  if (un > MAXN){ f = MAXN / nn; uN = MAXN; }
  float lg = artanh_c(uN) / fmaxf(uN, MINNRM);
  float t0 = lrelu(acc0 * f * lg, 0.01f);
  float t1 = lrelu(acc1 * f * lg, 0.01f);
  float nn2 = fmaxf(sqrtf(wsum(t0*t0 + t1*t1)), MINNRM);
  float un2 = tanhf(nn2);
  float f2, nm2v;
  if (un2 > MAXN){ f2 = MAXN / nn2; nm2v = MAXN; } else { f2 = un2 / nn2; nm2v = un2; }
  float2 o2; o2.x = t0 * f2; o2.y = t1 * f2;
  *(float2*)(hact + (size_t)n * 128 + 2 * lane) = o2;
  if (lane == 0) xn1[n] = nm2v;
}

// ---- ep2: mx2 -> ht2 (fp16, [n][feat][head] layout) + s2 dots ----
__global__ __launch_bounds__(256) void ep2(const float* __restrict__ mx2, const float* __restrict__ xn1,
    const float* __restrict__ hb, const float* __restrict__ ai, const float* __restrict__ aj,
    __half* __restrict__ ht2, float* __restrict__ s2i, float* __restrict__ s2j){
  int wave = threadIdx.x >> 6, lane = threadIdx.x & 63;
  int row = blockIdx.x * 4 + wave;
  if (row >= NN) return;
  size_t base = (size_t)row * 256;
  float v0 = mx2[base + lane], v1 = mx2[base + 64 + lane];
  float v2 = mx2[base + 128 + lane], v3 = mx2[base + 192 + lane];
  float xn = fmaxf(xn1[row], MINNRM);
  float r_art = artanh_c(xn);
  float mxn = fmaxf(sqrtf(wsum(v0*v0 + v1*v1 + v2*v2 + v3*v3)), MINNRM);
  float tn = tanhf(mxn / xn * r_art);
  float sc = tn / mxn;
  float res0 = v0*sc, res1 = v1*sc, res2 = v2*sc, res3 = v3*sc;
  float rn = tn;
  if (rn > MAXN){ float f = MAXN / rn; res0*=f; res1*=f; res2*=f; res3*=f; rn = MAXN; }
  float a2 = rn * rn;
  float hb0 = hb[lane], hb1v = hb[64 + lane], hb2v = hb[128 + lane], hb3 = hb[192 + lane];
  float b2 = hb[256];
  float ab = wsum(res0*hb0 + res1*hb1v + res2*hb2v + res3*hb3);
  float co1 = 1.f + 2.f * ab + b2;
  float co2 = 1.f - a2;
  float den = fmaxf(1.f + 2.f * ab + a2 * b2, MINNRM);
  float h0v = (co1*res0 + co2*hb0) / den;
  float h1v = (co1*res1 + co2*hb1v) / den;
  float h2v = (co1*res2 + co2*hb2v) / den;
  float h3v = (co1*res3 + co2*hb3) / den;
  float hn = fmaxf(sqrtf(wsum(h0v*h0v + h1v*h1v + h2v*h2v + h3v*h3v)), MINNRM);
  if (hn > MAXN){ float f = MAXN / hn; h0v*=f; h1v*=f; h2v*=f; h3v*=f; hn = MAXN; }
  float lf = artanh_c(hn) / hn;
  float t0 = h0v*lf, t1 = h1v*lf, t2 = h2v*lf, t3 = h3v*lf;
  union { __half2 hh[2]; float2 ff; } u;
  u.hh[0] = __floats2half2_rn(t0, t1);
  u.hh[1] = __floats2half2_rn(t2, t3);
  *(float2*)(ht2 + base + 4 * lane) = u.ff;
  float pi0 = wsum(t0 * ai[lane]);
  float pi1 = wsum(t1 * ai[64 + lane]);
  float pi2 = wsum(t2 * ai[128 + lane]);
  float pi3 = wsum(t3 * ai[192 + lane]);
  float pj0 = wsum(t0 * aj[lane]);
  float pj1 = wsum(t1 * aj[64 + lane]);
  float pj2 = wsum(t2 * aj[128 + lane]);
  float pj3 = wsum(t3 * aj[192 + lane]);
  if (lane == 0){
    s2i[row*4+0]=pi0; s2i[row*4+1]=pi1; s2i[row*4+2]=pi2; s2i[row*4+3]=pi3;
    s2j[row*4+0]=pj0; s2j[row*4+1]=pj1; s2j[row*4+2]=pj2; s2j[row*4+3]=pj3;
  }
}

// ---- agg2: flash softmax-aggregate (4 heads, mean) + hyp_act + logmap0 -> out ----
__global__ __launch_bounds__(256) void k_agg2(const int* __restrict__ rowptr, const int* __restrict__ col,
    const __half* __restrict__ ht2, const float* __restrict__ s2i, const float* __restrict__ s2j,
    float* __restrict__ out){
  __shared__ float wlds[4][64][4];
  int wave = threadIdx.x >> 6, lane = threadIdx.x & 63;
  int n = blockIdx.x * 4 + wave;
  if (n >= NN) return;
  int p0 = rowptr[n], p1 = rowptr[n + 1];
  float4 si = *(const float4*)(s2i + (size_t)n * 4);
  float m0=-1e30f,m1=-1e30f,m2=-1e30f,m3=-1e30f;
  float s0=0.f,s1=0.f,s2=0.f,s3=0.f;
  float a0=0.f,a1=0.f,a2=0.f,a3=0.f;
  for (int base = p0; base < p1; base += 64){
    int myE = base + lane;
    int d = 0;
    float q0=-1e30f,q1=-1e30f,q2=-1e30f,q3=-1e30f;
    if (myE < p1){
      d = col[myE];
      float4 sj = *(const float4*)(s2j + (size_t)d * 4);
      q0 = lrelu(si.x + sj.x, 0.2f);
      q1 = lrelu(si.y + sj.y, 0.2f);
      q2 = lrelu(si.z + sj.z, 0.2f);
      q3 = lrelu(si.w + sj.w, 0.2f);
    }
    float nm0 = fmaxf(m0, wmax(q0)), nm1 = fmaxf(m1, wmax(q1));
    float nm2 = fmaxf(m2, wmax(q2)), nm3 = fmaxf(m3, wmax(q3));
    float r0 = __expf(m0 - nm0), r1 = __expf(m1 - nm1);
    float r2 = __expf(m2 - nm2), r3 = __expf(m3 - nm3);
    float w0 = __expf(q0 - nm0), w1 = __expf(q1 - nm1);
    float w2 = __expf(q2 - nm2), w3 = __expf(q3 - nm3);
    s0 = s0 * r0 + wsum(w0); s1 = s1 * r1 + wsum(w1);
    s2 = s2 * r2 + wsum(w2); s3 = s3 * r3 + wsum(w3);
    m0 = nm0; m1 = nm1; m2 = nm2; m3 = nm3;
    a0 *= r0; a1 *= r1; a2 *= r2; a3 *= r3;
    *(float4*)&wlds[wave][lane][0] = make_float4(w0, w1, w2, w3);
    __builtin_amdgcn_wave_barrier();
    int cnt = min(p1 - base, 64);
    int q = 0;
    for (; q + 1 < cnt; q += 2){
      int dA = __builtin_amdgcn_readlane(d, q);
      int dB = __builtin_amdgcn_readlane(d, q + 1);
      float4 WA = *(const float4*)&wlds[wave][q][0];
      float4 WB = *(const float4*)&wlds[wave][q + 1][0];
      union { float2 ff; __half2 hh[2]; } uA, uB;
      uA.ff = *(const float2*)(ht2 + (size_t)dA * 256 + 4 * lane);
      uB.ff = *(const float2*)(ht2 + (size_t)dB * 256 + 4 * lane);
      float2 vA01 = __half22float2(uA.hh[0]), vA23 = __half22float2(uA.hh[1]);
      float2 vB01 = __half22float2(uB.hh[0]), vB23 = __half22float2(uB.hh[1]);
      a0 += WA.x * vA01.x + WB.x * vB01.x;
      a1 += WA.y * vA01.y + WB.y * vB01.y;
      a2 += WA.z * vA23.x + WB.z * vB23.x;
      a3 += WA.w * vA23.y + WB.w * vB23.y;
    }
    if (q < cnt){
      int dA = __builtin_amdgcn_readlane(d, q);
      float4 WA = *(const float4*)&wlds[wave][q][0];
      union { float2 ff; __half2 hh[2]; } uA;
      uA.ff = *(const float2*)(ht2 + (size_t)dA * 256 + 4 * lane);
      float2 vA01 = __half22float2(uA.hh[0]), vA23 = __half22float2(uA.hh[1]);
      a0 += WA.x * vA01.x;
      a1 += WA.y * vA01.y;
      a2 += WA.z * vA23.x;
      a3 += WA.w * vA23.y;
    }
    __builtin_amdgcn_wave_barrier();
  }
  a0 /= (s0 + 1e-16f); a1 /= (s1 + 1e-16f);
  a2 /= (s2 + 1e-16f); a3 /= (s3 + 1e-16f);
  float mean = 0.25f * (a0 + a1 + a2 + a3);
  float nn = fmaxf(sqrtf(wsum(mean * mean)), MINNRM);
  float un = tanhf(nn);
  float f = un / nn; float uN = un;
  if (un > MAXN){ f = MAXN / nn; uN = MAXN; }
  float lg = artanh_c(uN) / fmaxf(uN, MINNRM);
  float t = lrelu(mean * f * lg, 0.01f);
  float nn2 = fmaxf(sqrtf(wsum(t * t)), MINNRM);
  float un2 = tanhf(nn2);
  float f2 = (un2 > MAXN) ? (MAXN / nn2) : (un2 / nn2);
  float uN2 = fminf(un2, MAXN);
  float lg2 = artanh_c(uN2) / fmaxf(uN2, MINNRM);
  out[(size_t)n * 64 + lane] = t * f2 * lg2;
}

extern "C" void kernel_launch(void* const* d_in, const int* in_sizes, int n_in,
                              void* d_out, int out_size, void* d_ws, size_t ws_size,
                              hipStream_t stream){
  const float* x   = (const float*)d_in[0];
  const float* Wl  = (const float*)d_in[1];
  const float* bl  = (const float*)d_in[2];
  const float* W1  = (const float*)d_in[3];
  const float* b1  = (const float*)d_in[4];
  const float* ai1 = (const float*)d_in[5];
  const float* aj1 = (const float*)d_in[6];
  const float* W2  = (const float*)d_in[7];
  const float* b2  = (const float*)d_in[8];
  const float* ai2 = (const float*)d_in[9];
  const float* aj2 = (const float*)d_in[10];
  const int*   ei  = (const int*)d_in[11];
  float* out = (float*)d_out;
  float* ws  = (float*)d_ws;

  // slab layout (float units):
  //  h0    [0, 3.2M)          dead after kgemm1
  //  mx1   [3.2M, 9.6M)       dead after ep1
  //  ht1h  [9.6M, 12.8M)      fp16, dead after agg1
  //  hact  [12.8M, 19.2M)     dead after kgemm2
  //  mx2   [0, 12.8M)         (h0,mx1,ht1h dead) dead after ep2
  //  ht2h  [12.8M, 19.2M)     fp16, aliases dead hact
  float* h0     = ws;
  float* mx1    = ws + 3200000;
  __half* ht1h  = (__half*)(ws + 9600000);
  float* hact   = ws + 12800000;
  float* mx2    = ws;
  __half* ht2h  = (__half*)(ws + 12800000);
  float* xn0    = ws + 19200000;
  float* xn1    = ws + 19250000;
  float* s1i    = ws + 19300000;  // = s2i (s1 dead after agg1)
  float* s1j    = ws + 19500000;  // = s2j
  float* hb1    = ws + 19700000;
  float* hb2    = ws + 19700132;
  int* rowptr   = (int*)(ws + 19700392);  // NN+1
  int* cnt      = rowptr + NN + 1;        // NN (doubles as fill cursor)
  int* col      = cnt + NN;               // NE
  int* part     = col + NE;               // NN
  int* bsum     = part + NN;              // NBLK

  hipMemsetAsync(cnt, 0, NN * sizeof(int), stream);
  kbias<<<1, 256, 0, stream>>>(b1, 128, hb1);
  kbias<<<1, 256, 0, stream>>>(b2, 256, hb2);
  khist<<<(NE + 255) / 256, 256, 0, stream>>>(ei, cnt);
  kscan1<<<NBLK, SCAN_B, 0, stream>>>(cnt, part, bsum);
  kscan2<<<1, 128, 0, stream>>>(bsum);
  kscan3<<<NBLK, SCAN_B, 0, stream>>>(part, bsum, rowptr, cnt);
  kfill<<<(NE + 255) / 256, 256, 0, stream>>>(ei, cnt, col);
  k_g0<<<(NN + 255) / 256, 256, 0, stream>>>(x, Wl, bl, h0, xn0);
  kgemm<128, 64, 2, 2><<<(NN + 127) / 128, 256, 0, stream>>>(h0, W1, mx1, NN);
  ep1<<<(NN + 3) / 4, 256, 0, stream>>>(mx1, xn0, hb1, ai1, aj1, ht1h, s1i, s1j);
  k_agg1<<<(NN + 3) / 4, 256, 0, stream>>>(rowptr, col, ht1h, s1i, s1j, hact, xn1);
  kgemm<256, 128, 1, 4><<<(NN + 63) / 64, 256, 0, stream>>>(hact, W2, mx2, NN);
  ep2<<<(NN + 3) / 4, 256, 0, stream>>>(mx2, xn1, hb2, ai2, aj2, ht2h, s1i, s1j);
  k_agg2<<<(NN + 3) / 4, 256, 0, stream>>>(rowptr, col, ht2h, s1i, s1j, out);
}

// Round 5
// 435.112 us; speedup vs baseline: 1.9798x; 1.0868x over previous
//
#include <hip/hip_runtime.h>
#include <hip/hip_fp16.h>

#define NN 50000
#define NER 800000
#define NE 850000
#define MAXN 0.996f
#define MINNRM 1e-15f
#define SCAN_B 512
#define NBLK ((NN + SCAN_B - 1) / SCAN_B)   // 98

__device__ __forceinline__ float wsum(float v){
#pragma unroll
  for (int m = 32; m >= 1; m >>= 1) v += __shfl_xor(v, m, 64);
  return v;
}
__device__ __forceinline__ float wmax(float v){
#pragma unroll
  for (int m = 32; m >= 1; m >>= 1) v = fmaxf(v, __shfl_xor(v, m, 64));
  return v;
}
__device__ __forceinline__ float artanh_c(float t){
  t = fminf(t, 1.0f - 1e-7f);
  return 0.5f * (log1pf(t) - log1pf(-t));
}
__device__ __forceinline__ float lrelu(float t, float s){ return t >= 0.f ? t : s * t; }

// ---- bias: hb = proj(expmap0(b)); hbx = [hb(L), b2, hbai(4), hbaj(4)] ----
__global__ void kbias2(const float* __restrict__ b, const float* __restrict__ ai,
                       const float* __restrict__ aj, int L, int HS, float* __restrict__ hbx){
  __shared__ float red[256];
  __shared__ float hai[4], haj[4];
  int t = threadIdx.x;
  float v = (t < L) ? b[t] : 0.f;
  red[t] = v * v; __syncthreads();
  for (int s = 128; s; s >>= 1){ if (t < s) red[t] += red[t + s]; __syncthreads(); }
  float n  = fmaxf(sqrtf(red[0]), MINNRM);
  float un = tanhf(n);
  float nn = un;
  float f  = un / n;
  if (un > MAXN){ f = MAXN / n; nn = MAXN; }
  float hb = v * f;
  if (t < L) hbx[t] = hb;
  if (t < 4){ hai[t] = 0.f; haj[t] = 0.f; }
  __syncthreads();
  if (t < L){
    int h = t / HS;
    atomicAdd(&hai[h], hb * ai[t]);
    atomicAdd(&haj[h], hb * aj[t]);
  }
  __syncthreads();
  if (t == 0) hbx[L] = nn * nn;
  if (t < 4){ hbx[L + 1 + t] = hai[t]; hbx[L + 5 + t] = haj[t]; }
}

// ---- CSR build ----
__global__ void khist(const int* __restrict__ ei, int* __restrict__ cnt){
  int e = blockIdx.x * blockDim.x + threadIdx.x;
  if (e >= NE) return;
  int s = (e < NER) ? ei[e] : (e - NER);
  atomicAdd(&cnt[s], 1);
}

__global__ __launch_bounds__(SCAN_B) void kscan1(const int* __restrict__ cnt,
                                                 int* __restrict__ part, int* __restrict__ bsum){
  __shared__ int sh[SCAN_B];
  int t = threadIdx.x;
  int i = blockIdx.x * SCAN_B + t;
  int v = (i < NN) ? cnt[i] : 0;
  sh[t] = v; __syncthreads();
  for (int d = 1; d < SCAN_B; d <<= 1){
    int u = (t >= d) ? sh[t - d] : 0;
    __syncthreads();
    sh[t] += u;
    __syncthreads();
  }
  if (i < NN) part[i] = sh[t];
  if (t == SCAN_B - 1) bsum[blockIdx.x] = sh[t];
}

__global__ __launch_bounds__(128) void kscan2(int* __restrict__ bsum){
  __shared__ int sh[128];
  int t = threadIdx.x;
  int v = (t < NBLK) ? bsum[t] : 0;
  sh[t] = v; __syncthreads();
  for (int d = 1; d < 128; d <<= 1){
    int u = (t >= d) ? sh[t - d] : 0;
    __syncthreads();
    sh[t] += u;
    __syncthreads();
  }
  if (t < NBLK) bsum[t] = sh[t];
}

__global__ __launch_bounds__(SCAN_B) void kscan3(const int* __restrict__ part, const int* __restrict__ bsum,
                                                 int* __restrict__ rowptr, int* __restrict__ cursor){
  int t = threadIdx.x;
  int i = blockIdx.x * SCAN_B + t;
  if (i < NN){
    int base = blockIdx.x ? bsum[blockIdx.x - 1] : 0;
    int excl = base + part[i] - cursor[i];
    rowptr[i] = excl;
    cursor[i] = excl;
  }
  if (i == 0) rowptr[NN] = bsum[NBLK - 1];
}

__global__ void kfill(const int* __restrict__ ei, int* __restrict__ cursor, int* __restrict__ col){
  int e = blockIdx.x * blockDim.x + threadIdx.x;
  if (e >= NE) return;
  int s, d;
  if (e < NER){ s = ei[e]; d = ei[NER + e]; }
  else { s = e - NER; d = s; }
  int pos = atomicAdd(&cursor[s], 1);
  col[pos] = d;
}

// ---- G0 fused: h0 = proj(expmap0(x @ Wl^T + bl)) + xn0 ----
__global__ __launch_bounds__(256) void k_g0(const float* __restrict__ x, const float* __restrict__ Wl,
                                            const float* __restrict__ bl, float* __restrict__ h0,
                                            float* __restrict__ xn0){
  __shared__ float As[32][260];
  __shared__ float Bs[32][68];
  int tid = threadIdx.x;
  int wave = tid >> 6, lane = tid & 63;
  int lr = lane >> 3, lc = lane & 7;
  int row0 = blockIdx.x * 256;
  int r0 = wave * 64 + lr * 8;
  int c0 = lc * 8;
  float acc[8][8] = {};
  for (int k0 = 0; k0 < 128; k0 += 32){
    __syncthreads();
    for (int f = tid; f < 256 * 8; f += 256){
      int m = f >> 3, ko = (f & 7) * 4;
      int row = row0 + m;
      float4 v = make_float4(0.f,0.f,0.f,0.f);
      if (row < NN) v = *(const float4*)(x + (size_t)row * 128 + k0 + ko);
      As[ko+0][m]=v.x; As[ko+1][m]=v.y; As[ko+2][m]=v.z; As[ko+3][m]=v.w;
    }
    for (int f = tid; f < 64 * 8; f += 256){
      int n = f >> 3, ko = (f & 7) * 4;
      float4 v = *(const float4*)(Wl + (size_t)n * 128 + k0 + ko);
      Bs[ko+0][n]=v.x; Bs[ko+1][n]=v.y; Bs[ko+2][n]=v.z; Bs[ko+3][n]=v.w;
    }
    __syncthreads();
#pragma unroll 4
    for (int k = 0; k < 32; k++){
      float a[8], b[8];
      *(float4*)&a[0] = *(const float4*)&As[k][r0];
      *(float4*)&a[4] = *(const float4*)&As[k][r0+4];
      *(float4*)&b[0] = *(const float4*)&Bs[k][c0];
      *(float4*)&b[4] = *(const float4*)&Bs[k][c0+4];
#pragma unroll
      for (int i = 0; i < 8; i++)
#pragma unroll
        for (int j = 0; j < 8; j++)
          acc[i][j] = fmaf(a[i], b[j], acc[i][j]);
    }
  }
  float bb[8];
  *(float4*)&bb[0] = *(const float4*)(bl + c0);
  *(float4*)&bb[4] = *(const float4*)(bl + c0 + 4);
#pragma unroll
  for (int i = 0; i < 8; i++){
    float rs = 0.f;
#pragma unroll
    for (int j = 0; j < 8; j++){ acc[i][j] += bb[j]; rs = fmaf(acc[i][j], acc[i][j], rs); }
    rs += __shfl_xor(rs, 1, 64);
    rs += __shfl_xor(rs, 2, 64);
    rs += __shfl_xor(rs, 4, 64);
    float n  = fmaxf(sqrtf(rs), MINNRM);
    float un = tanhf(n);
    float f, nm;
    if (un > MAXN){ f = MAXN / n; nm = MAXN; } else { f = un / n; nm = un; }
    int row = row0 + r0 + i;
    if (row < NN){
#pragma unroll
      for (int j = 0; j < 8; j++) acc[i][j] *= f;
      float* cp = h0 + (size_t)row * 64 + c0;
      *(float4*)cp     = *(float4*)&acc[i][0];
      *(float4*)(cp+4) = *(float4*)&acc[i][4];
      if (lc == 0) xn0[row] = nm;
    }
  }
}

// ---- kg1f: mx1 = h0 @ W1^T fused with hyp_linear epilogue + logmap0 + s1 dots ----
// BM=128, N=128, K=64; waves (wr,wc) 2x2.
__global__ __launch_bounds__(256) void kg1f(const float* __restrict__ A, const float* __restrict__ B,
    const float* __restrict__ xn0, const float* __restrict__ hbx,
    const float* __restrict__ ai, const float* __restrict__ aj,
    __half* __restrict__ ht1, float* __restrict__ s1i, float* __restrict__ s1j){
  __shared__ float As[32][132];
  __shared__ float Bs[32][132];
  __shared__ float red[128][12];
  int tid = threadIdx.x, wave = tid >> 6, lane = tid & 63;
  int wr = wave >> 1, wc = wave & 1, lr = lane >> 3, lc = lane & 7;
  int row0 = blockIdx.x * 128;
  int r0 = wr * 64 + lr * 8, c0 = wc * 64 + lc * 8;
  float acc[8][8] = {};
  for (int k0 = 0; k0 < 64; k0 += 32){
    __syncthreads();
    for (int f = tid; f < 128 * 8; f += 256){
      int m = f >> 3, ko = (f & 7) * 4; int row = row0 + m;
      float4 v = make_float4(0.f,0.f,0.f,0.f);
      if (row < NN) v = *(const float4*)(A + (size_t)row * 64 + k0 + ko);
      As[ko+0][m]=v.x; As[ko+1][m]=v.y; As[ko+2][m]=v.z; As[ko+3][m]=v.w;
    }
    for (int f = tid; f < 128 * 8; f += 256){
      int nn_ = f >> 3, ko = (f & 7) * 4;
      float4 v = *(const float4*)(B + (size_t)nn_ * 64 + k0 + ko);
      Bs[ko+0][nn_]=v.x; Bs[ko+1][nn_]=v.y; Bs[ko+2][nn_]=v.z; Bs[ko+3][nn_]=v.w;
    }
    __syncthreads();
#pragma unroll 4
    for (int k = 0; k < 32; k++){
      float a[8], b[8];
      *(float4*)&a[0] = *(const float4*)&As[k][r0];
      *(float4*)&a[4] = *(const float4*)&As[k][r0+4];
      *(float4*)&b[0] = *(const float4*)&Bs[k][c0];
      *(float4*)&b[4] = *(const float4*)&Bs[k][c0+4];
#pragma unroll
      for (int i = 0; i < 8; i++)
#pragma unroll
        for (int j = 0; j < 8; j++)
          acc[i][j] = fmaf(a[i], b[j], acc[i][j]);
    }
  }
  float hbv[8], aiv[8], ajv[8];
  *(float4*)&hbv[0] = *(const float4*)(hbx + c0); *(float4*)&hbv[4] = *(const float4*)(hbx + c0 + 4);
  *(float4*)&aiv[0] = *(const float4*)(ai + c0);  *(float4*)&aiv[4] = *(const float4*)(ai + c0 + 4);
  *(float4*)&ajv[0] = *(const float4*)(aj + c0);  *(float4*)&ajv[4] = *(const float4*)(aj + c0 + 4);
  float b2 = hbx[128];
  int head = wc * 2 + (lc >> 2);
#pragma unroll
  for (int i = 0; i < 8; i++){
    float p1=0.f, p2=0.f, pai=0.f, paj=0.f;
#pragma unroll
    for (int j = 0; j < 8; j++){
      float a = acc[i][j];
      p1 += a*a; p2 += a*hbv[j]; pai += a*aiv[j]; paj += a*ajv[j];
    }
    p1 += __shfl_xor(p1,1,64); p1 += __shfl_xor(p1,2,64); p1 += __shfl_xor(p1,4,64);
    p2 += __shfl_xor(p2,1,64); p2 += __shfl_xor(p2,2,64); p2 += __shfl_xor(p2,4,64);
    pai += __shfl_xor(pai,1,64); pai += __shfl_xor(pai,2,64);
    paj += __shfl_xor(paj,1,64); paj += __shfl_xor(paj,2,64);
    int rloc = r0 + i;
    if (lc == 0){ red[rloc][wc] = p1; red[rloc][2+wc] = p2; }
    if ((lc & 3) == 0){ red[rloc][4+head] = pai; red[rloc][8+head] = paj; }
  }
  __syncthreads();
#pragma unroll
  for (int i = 0; i < 8; i++){
    int row = row0 + r0 + i;
    if (row >= NN) continue;
    int rloc = r0 + i;
    float S1 = red[rloc][0] + red[rloc][1];
    float S2 = red[rloc][2] + red[rloc][3];
    float xn = fmaxf(xn0[row], MINNRM);
    float r_art = artanh_c(xn);
    float mxn = fmaxf(sqrtf(S1), MINNRM);
    float tn = tanhf(mxn / xn * r_art);
    float sc = tn / mxn;
    float rn = tn;
    if (rn > MAXN){ sc *= MAXN / rn; rn = MAXN; }
    float a2r = rn * rn;
    float ab = sc * S2;
    float co1 = 1.f + 2.f*ab + b2, co2 = 1.f - a2r;
    float den = fmaxf(1.f + 2.f*ab + a2r*b2, MINNRM);
    float P = co1 * sc / den, Q = co2 / den;
    float hn2 = P*P*S1 + 2.f*P*Q*S2 + Q*Q*b2;
    float hn = fmaxf(sqrtf(hn2), MINNRM);
    if (hn > MAXN){ float R = MAXN / hn; P *= R; Q *= R; hn = MAXN; }
    float lf = artanh_c(hn) / hn;
    union { __half h[8]; float4 f4; } ho;
#pragma unroll
    for (int j = 0; j < 8; j++) ho.h[j] = __float2half(lf * (P * acc[i][j] + Q * hbv[j]));
    *(float4*)(ht1 + (size_t)row * 128 + c0) = ho.f4;
    if (lc == 0){
      float pi0 = lf * (P * red[rloc][4+2*wc]   + Q * hbx[129+2*wc]);
      float pi1 = lf * (P * red[rloc][4+2*wc+1] + Q * hbx[129+2*wc+1]);
      float pj0 = lf * (P * red[rloc][8+2*wc]   + Q * hbx[133+2*wc]);
      float pj1 = lf * (P * red[rloc][8+2*wc+1] + Q * hbx[133+2*wc+1]);
      s1i[row*4+2*wc] = pi0; s1i[row*4+2*wc+1] = pi1;
      s1j[row*4+2*wc] = pj0; s1j[row*4+2*wc+1] = pj1;
    }
  }
}

// ---- kg2f: mx2 = hact @ W2^T fused epilogue; ht2 linear [head*64+feat] fp16 ----
// BM=64, N=256, K=128; waves wc 0..3 (head wc).
__global__ __launch_bounds__(256) void kg2f(const float* __restrict__ A, const float* __restrict__ B,
    const float* __restrict__ xn1, const float* __restrict__ hbx,
    const float* __restrict__ ai, const float* __restrict__ aj,
    __half* __restrict__ ht2, float* __restrict__ s2i, float* __restrict__ s2j){
  __shared__ float As[32][68];
  __shared__ float Bs[32][260];
  __shared__ float red[64][16];
  int tid = threadIdx.x, wave = tid >> 6, lane = tid & 63;
  int wc = wave, lr = lane >> 3, lc = lane & 7;
  int row0 = blockIdx.x * 64;
  int r0 = lr * 8, c0 = wc * 64 + lc * 8;
  float acc[8][8] = {};
  for (int k0 = 0; k0 < 128; k0 += 32){
    __syncthreads();
    for (int f = tid; f < 64 * 8; f += 256){
      int m = f >> 3, ko = (f & 7) * 4; int row = row0 + m;
      float4 v = make_float4(0.f,0.f,0.f,0.f);
      if (row < NN) v = *(const float4*)(A + (size_t)row * 128 + k0 + ko);
      As[ko+0][m]=v.x; As[ko+1][m]=v.y; As[ko+2][m]=v.z; As[ko+3][m]=v.w;
    }
    for (int f = tid; f < 256 * 8; f += 256){
      int nn_ = f >> 3, ko = (f & 7) * 4;
      float4 v = *(const float4*)(B + (size_t)nn_ * 128 + k0 + ko);
      Bs[ko+0][nn_]=v.x; Bs[ko+1][nn_]=v.y; Bs[ko+2][nn_]=v.z; Bs[ko+3][nn_]=v.w;
    }
    __syncthreads();
#pragma unroll 4
    for (int k = 0; k < 32; k++){
      float a[8], b[8];
      *(float4*)&a[0] = *(const float4*)&As[k][r0];
      *(float4*)&a[4] = *(const float4*)&As[k][r0+4];
      *(float4*)&b[0] = *(const float4*)&Bs[k][c0];
      *(float4*)&b[4] = *(const float4*)&Bs[k][c0+4];
#pragma unroll
      for (int i = 0; i < 8; i++)
#pragma unroll
        for (int j = 0; j < 8; j++)
          acc[i][j] = fmaf(a[i], b[j], acc[i][j]);
    }
  }
  float hbv[8], aiv[8], ajv[8];
  *(float4*)&hbv[0] = *(const float4*)(hbx + c0); *(float4*)&hbv[4] = *(const float4*)(hbx + c0 + 4);
  *(float4*)&aiv[0] = *(const float4*)(ai + c0);  *(float4*)&aiv[4] = *(const float4*)(ai + c0 + 4);
  *(float4*)&ajv[0] = *(const float4*)(aj + c0);  *(float4*)&ajv[4] = *(const float4*)(aj + c0 + 4);
  float b2 = hbx[256];
#pragma unroll
  for (int i = 0; i < 8; i++){
    float p1=0.f, p2=0.f, pai=0.f, paj=0.f;
#pragma unroll
    for (int j = 0; j < 8; j++){
      float a = acc[i][j];
      p1 += a*a; p2 += a*hbv[j]; pai += a*aiv[j]; paj += a*ajv[j];
    }
    p1 += __shfl_xor(p1,1,64); p1 += __shfl_xor(p1,2,64); p1 += __shfl_xor(p1,4,64);
    p2 += __shfl_xor(p2,1,64); p2 += __shfl_xor(p2,2,64); p2 += __shfl_xor(p2,4,64);
    pai += __shfl_xor(pai,1,64); pai += __shfl_xor(pai,2,64); pai += __shfl_xor(pai,4,64);
    paj += __shfl_xor(paj,1,64); paj += __shfl_xor(paj,2,64); paj += __shfl_xor(paj,4,64);
    int rloc = r0 + i;
    if (lc == 0){ red[rloc][wc] = p1; red[rloc][4+wc] = p2; red[rloc][8+wc] = pai; red[rloc][12+wc] = paj; }
  }
  __syncthreads();
#pragma unroll
  for (int i = 0; i < 8; i++){
    int row = row0 + r0 + i;
    if (row >= NN) continue;
    int rloc = r0 + i;
    float S1 = red[rloc][0]+red[rloc][1]+red[rloc][2]+red[rloc][3];
    float S2 = red[rloc][4]+red[rloc][5]+red[rloc][6]+red[rloc][7];
    float xn = fmaxf(xn1[row], MINNRM);
    float r_art = artanh_c(xn);
    float mxn = fmaxf(sqrtf(S1), MINNRM);
    float tn = tanhf(mxn / xn * r_art);
    float sc = tn / mxn;
    float rn = tn;
    if (rn > MAXN){ sc *= MAXN / rn; rn = MAXN; }
    float a2r = rn * rn;
    float ab = sc * S2;
    float co1 = 1.f + 2.f*ab + b2, co2 = 1.f - a2r;
    float den = fmaxf(1.f + 2.f*ab + a2r*b2, MINNRM);
    float P = co1 * sc / den, Q = co2 / den;
    float hn2 = P*P*S1 + 2.f*P*Q*S2 + Q*Q*b2;
    float hn = fmaxf(sqrtf(hn2), MINNRM);
    if (hn > MAXN){ float R = MAXN / hn; P *= R; Q *= R; hn = MAXN; }
    float lf = artanh_c(hn) / hn;
    union { __half h[8]; float4 f4; } ho;
#pragma unroll
    for (int j = 0; j < 8; j++) ho.h[j] = __float2half(lf * (P * acc[i][j] + Q * hbv[j]));
    *(float4*)(ht2 + (size_t)row * 256 + c0) = ho.f4;
    if (lc == 0){
      float pi = lf * (P * red[rloc][8+wc]  + Q * hbx[257+wc]);
      float pj = lf * (P * red[rloc][12+wc] + Q * hbx[261+wc]);
      s2i[row*4+wc] = pi; s2j[row*4+wc] = pj;
    }
  }
}

// ---- agg1: flash softmax-aggregate (split-half gather) + hyp_act -> hact, xn1 ----
__global__ __launch_bounds__(256) void k_agg1(const int* __restrict__ rowptr, const int* __restrict__ col,
    const __half* __restrict__ ht1, const float* __restrict__ s1i, const float* __restrict__ s1j,
    float* __restrict__ hact, float* __restrict__ xn1){
  __shared__ float wlds[4][64][4];
  int wave = threadIdx.x >> 6, lane = threadIdx.x & 63;
  int n = blockIdx.x * 4 + wave;
  if (n >= NN) return;
  int p0 = rowptr[n], p1 = rowptr[n + 1];
  float4 si = *(const float4*)(s1i + (size_t)n * 4);
  int lL = lane & 31, hh = lL >> 3, half = lane >> 5;
  float m0=-1e30f,m1=-1e30f,m2=-1e30f,m3=-1e30f;
  float s0=0.f,s1=0.f,s2=0.f,s3=0.f;
  float ac0=0.f,ac1=0.f,ac2=0.f,ac3=0.f;
  for (int base = p0; base < p1; base += 64){
    int myE = base + lane;
    int d = 0;
    float a0=-1e30f,a1=-1e30f,a2=-1e30f,a3=-1e30f;
    if (myE < p1){
      d = col[myE];
      float4 sj = *(const float4*)(s1j + (size_t)d * 4);
      a0 = lrelu(si.x + sj.x, 0.2f);
      a1 = lrelu(si.y + sj.y, 0.2f);
      a2 = lrelu(si.z + sj.z, 0.2f);
      a3 = lrelu(si.w + sj.w, 0.2f);
    }
    float nm0 = fmaxf(m0, wmax(a0)), nm1 = fmaxf(m1, wmax(a1));
    float nm2 = fmaxf(m2, wmax(a2)), nm3 = fmaxf(m3, wmax(a3));
    float r0_ = __expf(m0 - nm0), r1_ = __expf(m1 - nm1);
    float r2_ = __expf(m2 - nm2), r3_ = __expf(m3 - nm3);
    float w0 = __expf(a0 - nm0), w1 = __expf(a1 - nm1);
    float w2 = __expf(a2 - nm2), w3 = __expf(a3 - nm3);
    s0 = s0 * r0_ + wsum(w0); s1 = s1 * r1_ + wsum(w1);
    s2 = s2 * r2_ + wsum(w2); s3 = s3 * r3_ + wsum(w3);
    m0 = nm0; m1 = nm1; m2 = nm2; m3 = nm3;
    float rsel = (hh==0)?r0_:(hh==1)?r1_:(hh==2)?r2_:r3_;
    ac0 *= rsel; ac1 *= rsel; ac2 *= rsel; ac3 *= rsel;
    *(float4*)&wlds[wave][lane][0] = make_float4(w0, w1, w2, w3);
    __builtin_amdgcn_wave_barrier();
    int cnt = min(p1 - base, 64);
    int pairs = (cnt + 1) >> 1;
    int p = 0;
    union U2 { uint2 u; __half2 h[2]; };
    for (; p + 1 < pairs; p += 2){
      int e0 = 2*p, e1 = 2*p + 2;
      int dA = __builtin_amdgcn_readlane(d, e0), dB = __builtin_amdgcn_readlane(d, e0+1);
      int dC = __builtin_amdgcn_readlane(d, e1), dD = __builtin_amdgcn_readlane(d, e1+1);
      int dx = half ? dB : dA;
      int dy = half ? dD : dC;
      float wx = wlds[wave][e0 + half][hh];
      float wy = wlds[wave][e1 + half][hh];
      U2 ux, uy;
      ux.u = *(const uint2*)(ht1 + (size_t)dx * 128 + 4*lL);
      uy.u = *(const uint2*)(ht1 + (size_t)dy * 128 + 4*lL);
      float2 x0 = __half22float2(ux.h[0]), x1 = __half22float2(ux.h[1]);
      float2 y0 = __half22float2(uy.h[0]), y1 = __half22float2(uy.h[1]);
      ac0 += wx*x0.x + wy*y0.x;
      ac1 += wx*x0.y + wy*y0.y;
      ac2 += wx*x1.x + wy*y1.x;
      ac3 += wx*x1.y + wy*y1.y;
    }
    if (p < pairs){
      int e0 = 2*p;
      int dA = __builtin_amdgcn_readlane(d, e0), dB = __builtin_amdgcn_readlane(d, e0+1);
      int dx = half ? dB : dA;
      float wx = wlds[wave][e0 + half][hh];
      U2 ux;
      ux.u = *(const uint2*)(ht1 + (size_t)dx * 128 + 4*lL);
      float2 x0 = __half22float2(ux.h[0]), x1 = __half22float2(ux.h[1]);
      ac0 += wx*x0.x; ac1 += wx*x0.y; ac2 += wx*x1.x; ac3 += wx*x1.y;
    }
    __builtin_amdgcn_wave_barrier();
  }
  ac0 += __shfl_xor(ac0, 32, 64);
  ac1 += __shfl_xor(ac1, 32, 64);
  ac2 += __shfl_xor(ac2, 32, 64);
  ac3 += __shfl_xor(ac3, 32, 64);
  float ssel = (hh==0)?s0:(hh==1)?s1:(hh==2)?s2:s3;
  float rinv = 1.f / (ssel + 1e-16f);
  ac0 *= rinv; ac1 *= rinv; ac2 *= rinv; ac3 *= rinv;
  float nn = fmaxf(sqrtf(0.5f * wsum(ac0*ac0 + ac1*ac1 + ac2*ac2 + ac3*ac3)), MINNRM);
  float un = tanhf(nn);
  float f_, uN;
  if (un > MAXN){ f_ = MAXN / nn; uN = MAXN; } else { f_ = un / nn; uN = un; }
  float lg = artanh_c(uN) / fmaxf(uN, MINNRM);
  float t0 = lrelu(ac0 * f_ * lg, 0.01f);
  float t1 = lrelu(ac1 * f_ * lg, 0.01f);
  float t2 = lrelu(ac2 * f_ * lg, 0.01f);
  float t3 = lrelu(ac3 * f_ * lg, 0.01f);
  float nn2 = fmaxf(sqrtf(0.5f * wsum(t0*t0 + t1*t1 + t2*t2 + t3*t3)), MINNRM);
  float un2 = tanhf(nn2);
  float f2, nm2v;
  if (un2 > MAXN){ f2 = MAXN / nn2; nm2v = MAXN; } else { f2 = un2 / nn2; nm2v = un2; }
  if (half == 0)
    *(float4*)(hact + (size_t)n * 128 + 4*lL) = make_float4(t0*f2, t1*f2, t2*f2, t3*f2);
  if (lane == 0) xn1[n] = nm2v;
}

// ---- agg2: flash softmax-aggregate (split-half, [head][feat] table) + mean + hyp_act + logmap0 ----
__global__ __launch_bounds__(256) void k_agg2(const int* __restrict__ rowptr, const int* __restrict__ col,
    const __half* __restrict__ ht2, const float* __restrict__ s2i, const float* __restrict__ s2j,
    float* __restrict__ out){
  __shared__ float wlds[4][64][4];
  int wave = threadIdx.x >> 6, lane = threadIdx.x & 63;
  int n = blockIdx.x * 4 + wave;
  if (n >= NN) return;
  int p0 = rowptr[n], p1 = rowptr[n + 1];
  float4 si = *(const float4*)(s2i + (size_t)n * 4);
  int lL = lane & 31, hh = lL >> 3, half = lane >> 5;
  float m0=-1e30f,m1=-1e30f,m2=-1e30f,m3=-1e30f;
  float s0=0.f,s1=0.f,s2=0.f,s3=0.f;
  float acc[8] = {};
  for (int base = p0; base < p1; base += 64){
    int myE = base + lane;
    int d = 0;
    float a0=-1e30f,a1=-1e30f,a2=-1e30f,a3=-1e30f;
    if (myE < p1){
      d = col[myE];
      float4 sj = *(const float4*)(s2j + (size_t)d * 4);
      a0 = lrelu(si.x + sj.x, 0.2f);
      a1 = lrelu(si.y + sj.y, 0.2f);
      a2 = lrelu(si.z + sj.z, 0.2f);
      a3 = lrelu(si.w + sj.w, 0.2f);
    }
    float nm0 = fmaxf(m0, wmax(a0)), nm1 = fmaxf(m1, wmax(a1));
    float nm2 = fmaxf(m2, wmax(a2)), nm3 = fmaxf(m3, wmax(a3));
    float r0_ = __expf(m0 - nm0), r1_ = __expf(m1 - nm1);
    float r2_ = __expf(m2 - nm2), r3_ = __expf(m3 - nm3);
    float w0 = __expf(a0 - nm0), w1 = __expf(a1 - nm1);
    float w2 = __expf(a2 - nm2), w3 = __expf(a3 - nm3);
    s0 = s0 * r0_ + wsum(w0); s1 = s1 * r1_ + wsum(w1);
    s2 = s2 * r2_ + wsum(w2); s3 = s3 * r3_ + wsum(w3);
    m0 = nm0; m1 = nm1; m2 = nm2; m3 = nm3;
    float rsel = (hh==0)?r0_:(hh==1)?r1_:(hh==2)?r2_:r3_;
#pragma unroll
    for (int j = 0; j < 8; j++) acc[j] *= rsel;
    *(float4*)&wlds[wave][lane][0] = make_float4(w0, w1, w2, w3);
    __builtin_amdgcn_wave_barrier();
    int cnt = min(p1 - base, 64);
    int pairs = (cnt + 1) >> 1;
    int p = 0;
    union U4 { uint4 u; __half2 h[4]; };
    for (; p + 1 < pairs; p += 2){
      int e0 = 2*p, e1 = 2*p + 2;
      int dA = __builtin_amdgcn_readlane(d, e0), dB = __builtin_amdgcn_readlane(d, e0+1);
      int dC = __builtin_amdgcn_readlane(d, e1), dD = __builtin_amdgcn_readlane(d, e1+1);
      int dx = half ? dB : dA;
      int dy = half ? dD : dC;
      float wx = wlds[wave][e0 + half][hh];
      float wy = wlds[wave][e1 + half][hh];
      U4 ux, uy;
      ux.u = *(const uint4*)(ht2 + (size_t)dx * 256 + 8*lL);
      uy.u = *(const uint4*)(ht2 + (size_t)dy * 256 + 8*lL);
#pragma unroll
      for (int j = 0; j < 4; j++){
        float2 xv = __half22float2(ux.h[j]);
        float2 yv = __half22float2(uy.h[j]);
        acc[2*j]   += wx*xv.x + wy*yv.x;
        acc[2*j+1] += wx*xv.y + wy*yv.y;
      }
    }
    if (p < pairs){
      int e0 = 2*p;
      int dA = __builtin_amdgcn_readlane(d, e0), dB = __builtin_amdgcn_readlane(d, e0+1);
      int dx = half ? dB : dA;
      float wx = wlds[wave][e0 + half][hh];
      U4 ux;
      ux.u = *(const uint4*)(ht2 + (size_t)dx * 256 + 8*lL);
#pragma unroll
      for (int j = 0; j < 4; j++){
        float2 xv = __half22float2(ux.h[j]);
        acc[2*j]   += wx*xv.x;
        acc[2*j+1] += wx*xv.y;
      }
    }
    __builtin_amdgcn_wave_barrier();
  }
#pragma unroll
  for (int j = 0; j < 8; j++) acc[j] += __shfl_xor(acc[j], 32, 64);
  float ssel = (hh==0)?s0:(hh==1)?s1:(hh==2)?s2:s3;
  float rinv = 1.f / (ssel + 1e-16f);
  float mj[8];
  float sum2 = 0.f;
#pragma unroll
  for (int j = 0; j < 8; j++){
    float v = acc[j] * rinv;
    v += __shfl_xor(v, 8, 64);
    v += __shfl_xor(v, 16, 64);
    mj[j] = 0.25f * v;
    sum2 += mj[j] * mj[j];
  }
  float nn = fmaxf(sqrtf(0.125f * wsum(sum2)), MINNRM);
  float un = tanhf(nn);
  float f_, uN;
  if (un > MAXN){ f_ = MAXN / nn; uN = MAXN; } else { f_ = un / nn; uN = un; }
  float lg = artanh_c(uN) / fmaxf(uN, MINNRM);
  float tt[8];
  float sum2b = 0.f;
#pragma unroll
  for (int j = 0; j < 8; j++){
    tt[j] = lrelu(mj[j] * f_ * lg, 0.01f);
    sum2b += tt[j] * tt[j];
  }
  float nn2 = fmaxf(sqrtf(0.125f * wsum(sum2b)), MINNRM);
  float un2 = tanhf(nn2);
  float f2 = (un2 > MAXN) ? (MAXN / nn2) : (un2 / nn2);
  float uN2 = fminf(un2, MAXN);
  float lg2 = artanh_c(uN2) / fmaxf(uN2, MINNRM);
  if (lane < 8){
    float o[8];
#pragma unroll
    for (int j = 0; j < 8; j++) o[j] = tt[j] * f2 * lg2;
    *(float4*)(out + (size_t)n * 64 + 8*lL)     = *(float4*)&o[0];
    *(float4*)(out + (size_t)n * 64 + 8*lL + 4) = *(float4*)&o[4];
  }
}

extern "C" void kernel_launch(void* const* d_in, const int* in_sizes, int n_in,
                              void* d_out, int out_size, void* d_ws, size_t ws_size,
                              hipStream_t stream){
  const float* x   = (const float*)d_in[0];
  const float* Wl  = (const float*)d_in[1];
  const float* bl  = (const float*)d_in[2];
  const float* W1  = (const float*)d_in[3];
  const float* b1  = (const float*)d_in[4];
  const float* ai1 = (const float*)d_in[5];
  const float* aj1 = (const float*)d_in[6];
  const float* W2  = (const float*)d_in[7];
  const float* b2  = (const float*)d_in[8];
  const float* ai2 = (const float*)d_in[9];
  const float* aj2 = (const float*)d_in[10];
  const int*   ei  = (const int*)d_in[11];
  float* out = (float*)d_out;
  float* ws  = (float*)d_ws;

  // layout (float units), no aliasing:
  float* h0     = ws;                       // [0, 3.2M)
  __half* ht1h  = (__half*)(ws + 3200000);  // [3.2M, 6.4M) as 6.4M halves
  float* hact   = ws + 6400000;             // [6.4M, 12.8M)
  __half* ht2h  = (__half*)(ws + 12800000); // [12.8M, 19.2M) as 12.8M halves
  float* xn0    = ws + 19200000;
  float* xn1    = ws + 19250000;
  float* s1i    = ws + 19300000;  // also s2i
  float* s1j    = ws + 19500000;  // also s2j
  float* hbx1   = ws + 19700000;  // 137 (pad 144)
  float* hbx2   = ws + 19700144;  // 265
  int* rowptr   = (int*)(ws + 19700416);  // NN+1
  int* cnt      = rowptr + NN + 1;        // NN (fill cursor)
  int* col      = cnt + NN;               // NE
  int* part     = col + NE;               // NN
  int* bsum     = part + NN;              // NBLK

  hipMemsetAsync(cnt, 0, NN * sizeof(int), stream);
  kbias2<<<1, 256, 0, stream>>>(b1, ai1, aj1, 128, 32, hbx1);
  kbias2<<<1, 256, 0, stream>>>(b2, ai2, aj2, 256, 64, hbx2);
  khist<<<(NE + 255) / 256, 256, 0, stream>>>(ei, cnt);
  kscan1<<<NBLK, SCAN_B, 0, stream>>>(cnt, part, bsum);
  kscan2<<<1, 128, 0, stream>>>(bsum);
  kscan3<<<NBLK, SCAN_B, 0, stream>>>(part, bsum, rowptr, cnt);
  kfill<<<(NE + 255) / 256, 256, 0, stream>>>(ei, cnt, col);
  k_g0<<<(NN + 255) / 256, 256, 0, stream>>>(x, Wl, bl, h0, xn0);
  kg1f<<<(NN + 127) / 128, 256, 0, stream>>>(h0, W1, xn0, hbx1, ai1, aj1, ht1h, s1i, s1j);
  k_agg1<<<(NN + 3) / 4, 256, 0, stream>>>(rowptr, col, ht1h, s1i, s1j, hact, xn1);
  kg2f<<<(NN + 63) / 64, 256, 0, stream>>>(hact, W2, xn1, hbx2, ai2, aj2, ht2h, s1i, s1j);
  k_agg2<<<(NN + 3) / 4, 256, 0, stream>>>(rowptr, col, ht2h, s1i, s1j, out);
}

// Round 6
// 404.507 us; speedup vs baseline: 2.1296x; 1.0757x over previous
//
#include <hip/hip_runtime.h>
#include <hip/hip_fp16.h>

#define NN 50000
#define NER 800000
#define NE 850000
#define MAXN 0.996f
#define MINNRM 1e-15f
#define SCAN_B 512
#define NBLK ((NN + SCAN_B - 1) / SCAN_B)   // 98

__device__ __forceinline__ float gsum16(float v){
  v += __shfl_xor(v, 1, 64); v += __shfl_xor(v, 2, 64);
  v += __shfl_xor(v, 4, 64); v += __shfl_xor(v, 8, 64);
  return v;
}
__device__ __forceinline__ float gmax16(float v){
  v = fmaxf(v, __shfl_xor(v, 1, 64)); v = fmaxf(v, __shfl_xor(v, 2, 64));
  v = fmaxf(v, __shfl_xor(v, 4, 64)); v = fmaxf(v, __shfl_xor(v, 8, 64));
  return v;
}
__device__ __forceinline__ float artanh_c(float t){
  t = fminf(t, 1.0f - 1e-7f);
  return 0.5f * (log1pf(t) - log1pf(-t));
}
__device__ __forceinline__ float lrelu(float t, float s){ return t >= 0.f ? t : s * t; }

// ---- bias: hb = proj(expmap0(b)); hbx = [hb(L), b2, hbai(4), hbaj(4)] ----
__global__ void kbias2(const float* __restrict__ b, const float* __restrict__ ai,
                       const float* __restrict__ aj, int L, int HS, float* __restrict__ hbx){
  __shared__ float red[256];
  __shared__ float hai[4], haj[4];
  int t = threadIdx.x;
  float v = (t < L) ? b[t] : 0.f;
  red[t] = v * v; __syncthreads();
  for (int s = 128; s; s >>= 1){ if (t < s) red[t] += red[t + s]; __syncthreads(); }
  float n  = fmaxf(sqrtf(red[0]), MINNRM);
  float un = tanhf(n);
  float nn = un;
  float f  = un / n;
  if (un > MAXN){ f = MAXN / n; nn = MAXN; }
  float hb = v * f;
  if (t < L) hbx[t] = hb;
  if (t < 4){ hai[t] = 0.f; haj[t] = 0.f; }
  __syncthreads();
  if (t < L){
    int h = t / HS;
    atomicAdd(&hai[h], hb * ai[t]);
    atomicAdd(&haj[h], hb * aj[t]);
  }
  __syncthreads();
  if (t == 0) hbx[L] = nn * nn;
  if (t < 4){ hbx[L + 1 + t] = hai[t]; hbx[L + 5 + t] = haj[t]; }
}

// ---- weight transpose: outp[k][n] = in[n][k] ----
__global__ void kT(const float* __restrict__ in, float* __restrict__ outp, int Nr, int Kc){
  int i = blockIdx.x * blockDim.x + threadIdx.x;
  if (i >= Nr * Kc) return;
  int n = i / Kc, k = i % Kc;
  outp[k * Nr + n] = in[i];
}

// ---- CSR build ----
__global__ void khist(const int* __restrict__ ei, int* __restrict__ cnt){
  int e = blockIdx.x * blockDim.x + threadIdx.x;
  if (e >= NE) return;
  int s = (e < NER) ? ei[e] : (e - NER);
  atomicAdd(&cnt[s], 1);
}

__global__ __launch_bounds__(SCAN_B) void kscan1(const int* __restrict__ cnt,
                                                 int* __restrict__ part, int* __restrict__ bsum){
  __shared__ int sh[SCAN_B];
  int t = threadIdx.x;
  int i = blockIdx.x * SCAN_B + t;
  int v = (i < NN) ? cnt[i] : 0;
  sh[t] = v; __syncthreads();
  for (int d = 1; d < SCAN_B; d <<= 1){
    int u = (t >= d) ? sh[t - d] : 0;
    __syncthreads();
    sh[t] += u;
    __syncthreads();
  }
  if (i < NN) part[i] = sh[t];
  if (t == SCAN_B - 1) bsum[blockIdx.x] = sh[t];
}

__global__ __launch_bounds__(128) void kscan2(int* __restrict__ bsum){
  __shared__ int sh[128];
  int t = threadIdx.x;
  int v = (t < NBLK) ? bsum[t] : 0;
  sh[t] = v; __syncthreads();
  for (int d = 1; d < 128; d <<= 1){
    int u = (t >= d) ? sh[t - d] : 0;
    __syncthreads();
    sh[t] += u;
    __syncthreads();
  }
  if (t < NBLK) bsum[t] = sh[t];
}

__global__ __launch_bounds__(SCAN_B) void kscan3(const int* __restrict__ part, const int* __restrict__ bsum,
                                                 int* __restrict__ rowptr, int* __restrict__ cursor){
  int t = threadIdx.x;
  int i = blockIdx.x * SCAN_B + t;
  if (i < NN){
    int base = blockIdx.x ? bsum[blockIdx.x - 1] : 0;
    int excl = base + part[i] - cursor[i];
    rowptr[i] = excl;
    cursor[i] = excl;
  }
  if (i == 0) rowptr[NN] = bsum[NBLK - 1];
}

__global__ void kfill(const int* __restrict__ ei, int* __restrict__ cursor, int* __restrict__ col){
  int e = blockIdx.x * blockDim.x + threadIdx.x;
  if (e >= NE) return;
  int s, d;
  if (e < NER){ s = ei[e]; d = ei[NER + e]; }
  else { s = e - NER; d = s; }
  int pos = atomicAdd(&cursor[s], 1);
  col[pos] = d;
}

// ---- k_g0: h0 = proj(expmap0(x @ Wl^T + bl)) + xn0.  BM=256, BK=16, Wlt[128][64] ----
__global__ __launch_bounds__(256) void k_g0(const float* __restrict__ x, const float* __restrict__ Wlt,
                                            const float* __restrict__ bl, float* __restrict__ h0,
                                            float* __restrict__ xn0){
  __shared__ float As[16][260];
  __shared__ float Bs[16][68];
  int tid = threadIdx.x;
  int wave = tid >> 6, lane = tid & 63;
  int lr = lane >> 3, lc = lane & 7;
  int row0 = blockIdx.x * 256;
  int r0 = wave * 64 + lr * 8;
  int c0 = lc * 8;
  float acc[8][8] = {};
  for (int k0 = 0; k0 < 128; k0 += 16){
    __syncthreads();
    for (int f = tid; f < 1024; f += 256){
      int m = f >> 2, ko = (f & 3) * 4;
      int row = row0 + m;
      float4 v = make_float4(0.f,0.f,0.f,0.f);
      if (row < NN) v = *(const float4*)(x + (size_t)row * 128 + k0 + ko);
      As[ko+0][m]=v.x; As[ko+1][m]=v.y; As[ko+2][m]=v.z; As[ko+3][m]=v.w;
    }
    {
      int kk = tid >> 4, n4 = (tid & 15) * 4;
      *(float4*)&Bs[kk][n4] = *(const float4*)(Wlt + (size_t)(k0 + kk) * 64 + n4);
    }
    __syncthreads();
#pragma unroll
    for (int k = 0; k < 16; k++){
      float a[8], b[8];
      *(float4*)&a[0] = *(const float4*)&As[k][r0];
      *(float4*)&a[4] = *(const float4*)&As[k][r0+4];
      *(float4*)&b[0] = *(const float4*)&Bs[k][c0];
      *(float4*)&b[4] = *(const float4*)&Bs[k][c0+4];
#pragma unroll
      for (int i = 0; i < 8; i++)
#pragma unroll
        for (int j = 0; j < 8; j++)
          acc[i][j] = fmaf(a[i], b[j], acc[i][j]);
    }
  }
  float bb[8];
  *(float4*)&bb[0] = *(const float4*)(bl + c0);
  *(float4*)&bb[4] = *(const float4*)(bl + c0 + 4);
#pragma unroll
  for (int i = 0; i < 8; i++){
    float rs = 0.f;
#pragma unroll
    for (int j = 0; j < 8; j++){ acc[i][j] += bb[j]; rs = fmaf(acc[i][j], acc[i][j], rs); }
    rs += __shfl_xor(rs, 1, 64);
    rs += __shfl_xor(rs, 2, 64);
    rs += __shfl_xor(rs, 4, 64);
    float n  = fmaxf(sqrtf(rs), MINNRM);
    float un = tanhf(n);
    float f, nm;
    if (un > MAXN){ f = MAXN / n; nm = MAXN; } else { f = un / n; nm = un; }
    int row = row0 + r0 + i;
    if (row < NN){
#pragma unroll
      for (int j = 0; j < 8; j++) acc[i][j] *= f;
      float* cp = h0 + (size_t)row * 64 + c0;
      *(float4*)cp     = *(float4*)&acc[i][0];
      *(float4*)(cp+4) = *(float4*)&acc[i][4];
      if (lc == 0) xn0[row] = nm;
    }
  }
}

// ---- kg1f: hyp_linear layer1 fused. BM=128, N=128, K=64, BK=16, W1t[64][128] ----
__global__ __launch_bounds__(256) void kg1f(const float* __restrict__ A, const float* __restrict__ W1t,
    const float* __restrict__ xn0, const float* __restrict__ hbx,
    const float* __restrict__ ai, const float* __restrict__ aj,
    __half* __restrict__ ht1, float* __restrict__ s1i, float* __restrict__ s1j){
  __shared__ float As[16][132];
  __shared__ float Bs[16][132];
  __shared__ float red[128][12];
  int tid = threadIdx.x, wave = tid >> 6, lane = tid & 63;
  int wr = wave >> 1, wc = wave & 1, lr = lane >> 3, lc = lane & 7;
  int row0 = blockIdx.x * 128;
  int r0 = wr * 64 + lr * 8, c0 = wc * 64 + lc * 8;
  float acc[8][8] = {};
  for (int k0 = 0; k0 < 64; k0 += 16){
    __syncthreads();
    for (int f = tid; f < 512; f += 256){
      int m = f >> 2, ko = (f & 3) * 4; int row = row0 + m;
      float4 v = make_float4(0.f,0.f,0.f,0.f);
      if (row < NN) v = *(const float4*)(A + (size_t)row * 64 + k0 + ko);
      As[ko+0][m]=v.x; As[ko+1][m]=v.y; As[ko+2][m]=v.z; As[ko+3][m]=v.w;
    }
    for (int f = tid; f < 512; f += 256){
      int kk = f >> 5, n4 = (f & 31) * 4;
      *(float4*)&Bs[kk][n4] = *(const float4*)(W1t + (size_t)(k0 + kk) * 128 + n4);
    }
    __syncthreads();
#pragma unroll
    for (int k = 0; k < 16; k++){
      float a[8], b[8];
      *(float4*)&a[0] = *(const float4*)&As[k][r0];
      *(float4*)&a[4] = *(const float4*)&As[k][r0+4];
      *(float4*)&b[0] = *(const float4*)&Bs[k][c0];
      *(float4*)&b[4] = *(const float4*)&Bs[k][c0+4];
#pragma unroll
      for (int i = 0; i < 8; i++)
#pragma unroll
        for (int j = 0; j < 8; j++)
          acc[i][j] = fmaf(a[i], b[j], acc[i][j]);
    }
  }
  float hbv[8], aiv[8], ajv[8];
  *(float4*)&hbv[0] = *(const float4*)(hbx + c0); *(float4*)&hbv[4] = *(const float4*)(hbx + c0 + 4);
  *(float4*)&aiv[0] = *(const float4*)(ai + c0);  *(float4*)&aiv[4] = *(const float4*)(ai + c0 + 4);
  *(float4*)&ajv[0] = *(const float4*)(aj + c0);  *(float4*)&ajv[4] = *(const float4*)(aj + c0 + 4);
  float b2 = hbx[128];
  int head = wc * 2 + (lc >> 2);
#pragma unroll
  for (int i = 0; i < 8; i++){
    float p1=0.f, p2=0.f, pai=0.f, paj=0.f;
#pragma unroll
    for (int j = 0; j < 8; j++){
      float a = acc[i][j];
      p1 += a*a; p2 += a*hbv[j]; pai += a*aiv[j]; paj += a*ajv[j];
    }
    p1 += __shfl_xor(p1,1,64); p1 += __shfl_xor(p1,2,64); p1 += __shfl_xor(p1,4,64);
    p2 += __shfl_xor(p2,1,64); p2 += __shfl_xor(p2,2,64); p2 += __shfl_xor(p2,4,64);
    pai += __shfl_xor(pai,1,64); pai += __shfl_xor(pai,2,64);
    paj += __shfl_xor(paj,1,64); paj += __shfl_xor(paj,2,64);
    int rloc = r0 + i;
    if (lc == 0){ red[rloc][wc] = p1; red[rloc][2+wc] = p2; }
    if ((lc & 3) == 0){ red[rloc][4+head] = pai; red[rloc][8+head] = paj; }
  }
  __syncthreads();
#pragma unroll
  for (int i = 0; i < 8; i++){
    int row = row0 + r0 + i;
    if (row >= NN) continue;
    int rloc = r0 + i;
    float S1 = red[rloc][0] + red[rloc][1];
    float S2 = red[rloc][2] + red[rloc][3];
    float xn = fmaxf(xn0[row], MINNRM);
    float r_art = artanh_c(xn);
    float mxn = fmaxf(sqrtf(S1), MINNRM);
    float tn = tanhf(mxn / xn * r_art);
    float sc = tn / mxn;
    float rn = tn;
    if (rn > MAXN){ sc *= MAXN / rn; rn = MAXN; }
    float a2r = rn * rn;
    float ab = sc * S2;
    float co1 = 1.f + 2.f*ab + b2, co2 = 1.f - a2r;
    float den = fmaxf(1.f + 2.f*ab + a2r*b2, MINNRM);
    float P = co1 * sc / den, Q = co2 / den;
    float hn2 = P*P*S1 + 2.f*P*Q*S2 + Q*Q*b2;
    float hn = fmaxf(sqrtf(hn2), MINNRM);
    if (hn > MAXN){ float R = MAXN / hn; P *= R; Q *= R; hn = MAXN; }
    float lf = artanh_c(hn) / hn;
    union { __half h[8]; float4 f4; } ho;
#pragma unroll
    for (int j = 0; j < 8; j++) ho.h[j] = __float2half(lf * (P * acc[i][j] + Q * hbv[j]));
    *(float4*)(ht1 + (size_t)row * 128 + c0) = ho.f4;
    if (lc == 0){
      float pi0 = lf * (P * red[rloc][4+2*wc]   + Q * hbx[129+2*wc]);
      float pi1 = lf * (P * red[rloc][4+2*wc+1] + Q * hbx[129+2*wc+1]);
      float pj0 = lf * (P * red[rloc][8+2*wc]   + Q * hbx[133+2*wc]);
      float pj1 = lf * (P * red[rloc][8+2*wc+1] + Q * hbx[133+2*wc+1]);
      s1i[row*4+2*wc] = pi0; s1i[row*4+2*wc+1] = pi1;
      s1j[row*4+2*wc] = pj0; s1j[row*4+2*wc+1] = pj1;
    }
  }
}

// ---- kg2f: hyp_linear layer2 fused. BM=64, N=256, K=128, BK=16, W2t[128][256] ----
__global__ __launch_bounds__(256) void kg2f(const float* __restrict__ A, const float* __restrict__ W2t,
    const float* __restrict__ xn1, const float* __restrict__ hbx,
    const float* __restrict__ ai, const float* __restrict__ aj,
    __half* __restrict__ ht2, float* __restrict__ s2i, float* __restrict__ s2j){
  __shared__ float As[16][68];
  __shared__ float Bs[16][260];
  __shared__ float red[64][16];
  int tid = threadIdx.x, wave = tid >> 6, lane = tid & 63;
  int wc = wave, lr = lane >> 3, lc = lane & 7;
  int row0 = blockIdx.x * 64;
  int r0 = lr * 8, c0 = wc * 64 + lc * 8;
  float acc[8][8] = {};
  for (int k0 = 0; k0 < 128; k0 += 16){
    __syncthreads();
    {
      int m = tid >> 2, ko = (tid & 3) * 4; int row = row0 + m;
      float4 v = make_float4(0.f,0.f,0.f,0.f);
      if (row < NN) v = *(const float4*)(A + (size_t)row * 128 + k0 + ko);
      As[ko+0][m]=v.x; As[ko+1][m]=v.y; As[ko+2][m]=v.z; As[ko+3][m]=v.w;
    }
    for (int f = tid; f < 1024; f += 256){
      int kk = f >> 6, n4 = (f & 63) * 4;
      *(float4*)&Bs[kk][n4] = *(const float4*)(W2t + (size_t)(k0 + kk) * 256 + n4);
    }
    __syncthreads();
#pragma unroll
    for (int k = 0; k < 16; k++){
      float a[8], b[8];
      *(float4*)&a[0] = *(const float4*)&As[k][r0];
      *(float4*)&a[4] = *(const float4*)&As[k][r0+4];
      *(float4*)&b[0] = *(const float4*)&Bs[k][c0];
      *(float4*)&b[4] = *(const float4*)&Bs[k][c0+4];
#pragma unroll
      for (int i = 0; i < 8; i++)
#pragma unroll
        for (int j = 0; j < 8; j++)
          acc[i][j] = fmaf(a[i], b[j], acc[i][j]);
    }
  }
  float hbv[8], aiv[8], ajv[8];
  *(float4*)&hbv[0] = *(const float4*)(hbx + c0); *(float4*)&hbv[4] = *(const float4*)(hbx + c0 + 4);
  *(float4*)&aiv[0] = *(const float4*)(ai + c0);  *(float4*)&aiv[4] = *(const float4*)(ai + c0 + 4);
  *(float4*)&ajv[0] = *(const float4*)(aj + c0);  *(float4*)&ajv[4] = *(const float4*)(aj + c0 + 4);
  float b2 = hbx[256];
#pragma unroll
  for (int i = 0; i < 8; i++){
    float p1=0.f, p2=0.f, pai=0.f, paj=0.f;
#pragma unroll
    for (int j = 0; j < 8; j++){
      float a = acc[i][j];
      p1 += a*a; p2 += a*hbv[j]; pai += a*aiv[j]; paj += a*ajv[j];
    }
    p1 += __shfl_xor(p1,1,64); p1 += __shfl_xor(p1,2,64); p1 += __shfl_xor(p1,4,64);
    p2 += __shfl_xor(p2,1,64); p2 += __shfl_xor(p2,2,64); p2 += __shfl_xor(p2,4,64);
    pai += __shfl_xor(pai,1,64); pai += __shfl_xor(pai,2,64); pai += __shfl_xor(pai,4,64);
    paj += __shfl_xor(paj,1,64); paj += __shfl_xor(paj,2,64); paj += __shfl_xor(paj,4,64);
    int rloc = r0 + i;
    if (lc == 0){ red[rloc][wc] = p1; red[rloc][4+wc] = p2; red[rloc][8+wc] = pai; red[rloc][12+wc] = paj; }
  }
  __syncthreads();
#pragma unroll
  for (int i = 0; i < 8; i++){
    int row = row0 + r0 + i;
    if (row >= NN) continue;
    int rloc = r0 + i;
    float S1 = red[rloc][0]+red[rloc][1]+red[rloc][2]+red[rloc][3];
    float S2 = red[rloc][4]+red[rloc][5]+red[rloc][6]+red[rloc][7];
    float xn = fmaxf(xn1[row], MINNRM);
    float r_art = artanh_c(xn);
    float mxn = fmaxf(sqrtf(S1), MINNRM);
    float tn = tanhf(mxn / xn * r_art);
    float sc = tn / mxn;
    float rn = tn;
    if (rn > MAXN){ sc *= MAXN / rn; rn = MAXN; }
    float a2r = rn * rn;
    float ab = sc * S2;
    float co1 = 1.f + 2.f*ab + b2, co2 = 1.f - a2r;
    float den = fmaxf(1.f + 2.f*ab + a2r*b2, MINNRM);
    float P = co1 * sc / den, Q = co2 / den;
    float hn2 = P*P*S1 + 2.f*P*Q*S2 + Q*Q*b2;
    float hn = fmaxf(sqrtf(hn2), MINNRM);
    if (hn > MAXN){ float R = MAXN / hn; P *= R; Q *= R; hn = MAXN; }
    float lf = artanh_c(hn) / hn;
    union { __half h[8]; float4 f4; } ho;
#pragma unroll
    for (int j = 0; j < 8; j++) ho.h[j] = __float2half(lf * (P * acc[i][j] + Q * hbv[j]));
    *(float4*)(ht2 + (size_t)row * 256 + c0) = ho.f4;
    if (lc == 0){
      float pi = lf * (P * red[rloc][8+wc]  + Q * hbx[257+wc]);
      float pj = lf * (P * red[rloc][12+wc] + Q * hbx[261+wc]);
      s2i[row*4+wc] = pi; s2j[row*4+wc] = pj;
    }
  }
}

// ---- agg1: 16-lane group per node; flash softmax-aggregate + hyp_act -> hact, xn1 ----
__global__ __launch_bounds__(256) void k_agg1(const int* __restrict__ rowptr, const int* __restrict__ col,
    const __half* __restrict__ ht1, const float* __restrict__ s1i, const float* __restrict__ s1j,
    float* __restrict__ hact, float* __restrict__ xn1){
  __shared__ int   sc[4][64];
  __shared__ float sw[4][64][5];
  int tid = threadIdx.x, wave = tid >> 6, lane = tid & 63;
  int g = lane >> 4, l = lane & 15, hh = l >> 2;
  int n = blockIdx.x * 16 + wave * 4 + g;   // NN % 16 == 0
  int p0 = rowptr[n], p1 = rowptr[n + 1];
  float4 si = *(const float4*)(s1i + (size_t)n * 4);
  float m0=-1e30f,m1=-1e30f,m2=-1e30f,m3=-1e30f;
  float s0=0.f,s1=0.f,s2=0.f,s3=0.f;
  float acc[8] = {};
  union U4 { uint4 u; __half2 h[4]; };
  for (int base = p0; base < p1; base += 16){
    int myE = base + l;
    int d = 0;
    float a0=-1e30f,a1=-1e30f,a2=-1e30f,a3=-1e30f;
    if (myE < p1){
      d = col[myE];
      float4 sj = *(const float4*)(s1j + (size_t)d * 4);
      a0 = lrelu(si.x + sj.x, 0.2f);
      a1 = lrelu(si.y + sj.y, 0.2f);
      a2 = lrelu(si.z + sj.z, 0.2f);
      a3 = lrelu(si.w + sj.w, 0.2f);
    }
    float nm0 = fmaxf(m0, gmax16(a0)), nm1 = fmaxf(m1, gmax16(a1));
    float nm2 = fmaxf(m2, gmax16(a2)), nm3 = fmaxf(m3, gmax16(a3));
    float r0_ = __expf(m0 - nm0), r1_ = __expf(m1 - nm1);
    float r2_ = __expf(m2 - nm2), r3_ = __expf(m3 - nm3);
    float w0 = __expf(a0 - nm0), w1 = __expf(a1 - nm1);
    float w2 = __expf(a2 - nm2), w3 = __expf(a3 - nm3);
    s0 = s0 * r0_ + gsum16(w0); s1 = s1 * r1_ + gsum16(w1);
    s2 = s2 * r2_ + gsum16(w2); s3 = s3 * r3_ + gsum16(w3);
    m0 = nm0; m1 = nm1; m2 = nm2; m3 = nm3;
    float rsel = (hh==0)?r0_:(hh==1)?r1_:(hh==2)?r2_:r3_;
#pragma unroll
    for (int j = 0; j < 8; j++) acc[j] *= rsel;
    sc[wave][g*16 + l] = d;
    sw[wave][g*16 + l][0] = w0; sw[wave][g*16 + l][1] = w1;
    sw[wave][g*16 + l][2] = w2; sw[wave][g*16 + l][3] = w3;
    __builtin_amdgcn_wave_barrier();
    int cnt = min(p1 - base, 16);
    int e = 0;
    for (; e + 1 < cnt; e += 2){
      int dA = sc[wave][g*16 + e], dB = sc[wave][g*16 + e + 1];
      float wA = sw[wave][g*16 + e][hh], wB = sw[wave][g*16 + e + 1][hh];
      U4 uA, uB;
      uA.u = *(const uint4*)(ht1 + (size_t)dA * 128 + 8*l);
      uB.u = *(const uint4*)(ht1 + (size_t)dB * 128 + 8*l);
#pragma unroll
      for (int j = 0; j < 4; j++){
        float2 xa = __half22float2(uA.h[j]);
        float2 xb = __half22float2(uB.h[j]);
        acc[2*j]   += wA*xa.x + wB*xb.x;
        acc[2*j+1] += wA*xa.y + wB*xb.y;
      }
    }
    if (e < cnt){
      int dA = sc[wave][g*16 + e];
      float wA = sw[wave][g*16 + e][hh];
      U4 uA;
      uA.u = *(const uint4*)(ht1 + (size_t)dA * 128 + 8*l);
#pragma unroll
      for (int j = 0; j < 4; j++){
        float2 xa = __half22float2(uA.h[j]);
        acc[2*j]   += wA*xa.x;
        acc[2*j+1] += wA*xa.y;
      }
    }
    __builtin_amdgcn_wave_barrier();
  }
  float ssel = (hh==0)?s0:(hh==1)?s1:(hh==2)?s2:s3;
  float rinv = 1.f / (ssel + 1e-16f);
  float sum2 = 0.f;
#pragma unroll
  for (int j = 0; j < 8; j++){ acc[j] *= rinv; sum2 = fmaf(acc[j], acc[j], sum2); }
  sum2 = gsum16(sum2);
  float nn = fmaxf(sqrtf(sum2), MINNRM);
  float un = tanhf(nn);
  float f_, uN;
  if (un > MAXN){ f_ = MAXN / nn; uN = MAXN; } else { f_ = un / nn; uN = un; }
  float lg = artanh_c(uN) / fmaxf(uN, MINNRM);
  float tt[8]; float sum2b = 0.f;
#pragma unroll
  for (int j = 0; j < 8; j++){ tt[j] = lrelu(acc[j] * f_ * lg, 0.01f); sum2b = fmaf(tt[j], tt[j], sum2b); }
  sum2b = gsum16(sum2b);
  float nn2 = fmaxf(sqrtf(sum2b), MINNRM);
  float un2 = tanhf(nn2);
  float f2, nm2v;
  if (un2 > MAXN){ f2 = MAXN / nn2; nm2v = MAXN; } else { f2 = un2 / nn2; nm2v = un2; }
  float o[8];
#pragma unroll
  for (int j = 0; j < 8; j++) o[j] = tt[j] * f2;
  *(float4*)(hact + (size_t)n * 128 + 8*l)     = *(float4*)&o[0];
  *(float4*)(hact + (size_t)n * 128 + 8*l + 4) = *(float4*)&o[4];
  if (l == 0) xn1[n] = nm2v;
}

// ---- agg2: 16-lane group per node; mean heads + hyp_act + logmap0 -> out ----
__global__ __launch_bounds__(256) void k_agg2(const int* __restrict__ rowptr, const int* __restrict__ col,
    const __half* __restrict__ ht2, const float* __restrict__ s2i, const float* __restrict__ s2j,
    float* __restrict__ out){
  __shared__ int   sc[4][64];
  __shared__ float sw[4][64][5];
  int tid = threadIdx.x, wave = tid >> 6, lane = tid & 63;
  int g = lane >> 4, l = lane & 15, hh = l >> 2;
  int n = blockIdx.x * 16 + wave * 4 + g;
  int p0 = rowptr[n], p1 = rowptr[n + 1];
  float4 si = *(const float4*)(s2i + (size_t)n * 4);
  float m0=-1e30f,m1=-1e30f,m2=-1e30f,m3=-1e30f;
  float s0=0.f,s1=0.f,s2=0.f,s3=0.f;
  float acc[16] = {};
  union U4 { uint4 u; __half2 h[4]; };
  for (int base = p0; base < p1; base += 16){
    int myE = base + l;
    int d = 0;
    float a0=-1e30f,a1=-1e30f,a2=-1e30f,a3=-1e30f;
    if (myE < p1){
      d = col[myE];
      float4 sj = *(const float4*)(s2j + (size_t)d * 4);
      a0 = lrelu(si.x + sj.x, 0.2f);
      a1 = lrelu(si.y + sj.y, 0.2f);
      a2 = lrelu(si.z + sj.z, 0.2f);
      a3 = lrelu(si.w + sj.w, 0.2f);
    }
    float nm0 = fmaxf(m0, gmax16(a0)), nm1 = fmaxf(m1, gmax16(a1));
    float nm2 = fmaxf(m2, gmax16(a2)), nm3 = fmaxf(m3, gmax16(a3));
    float r0_ = __expf(m0 - nm0), r1_ = __expf(m1 - nm1);
    float r2_ = __expf(m2 - nm2), r3_ = __expf(m3 - nm3);
    float w0 = __expf(a0 - nm0), w1 = __expf(a1 - nm1);
    float w2 = __expf(a2 - nm2), w3 = __expf(a3 - nm3);
    s0 = s0 * r0_ + gsum16(w0); s1 = s1 * r1_ + gsum16(w1);
    s2 = s2 * r2_ + gsum16(w2); s3 = s3 * r3_ + gsum16(w3);
    m0 = nm0; m1 = nm1; m2 = nm2; m3 = nm3;
    float rsel = (hh==0)?r0_:(hh==1)?r1_:(hh==2)?r2_:r3_;
#pragma unroll
    for (int j = 0; j < 16; j++) acc[j] *= rsel;
    sc[wave][g*16 + l] = d;
    sw[wave][g*16 + l][0] = w0; sw[wave][g*16 + l][1] = w1;
    sw[wave][g*16 + l][2] = w2; sw[wave][g*16 + l][3] = w3;
    __builtin_amdgcn_wave_barrier();
    int cnt = min(p1 - base, 16);
    int e = 0;
    for (; e + 1 < cnt; e += 2){
      int dA = sc[wave][g*16 + e], dB = sc[wave][g*16 + e + 1];
      float wA = sw[wave][g*16 + e][hh], wB = sw[wave][g*16 + e + 1][hh];
      U4 uA0, uA1, uB0, uB1;
      const __half* pA = ht2 + (size_t)dA * 256 + 16*l;
      const __half* pB = ht2 + (size_t)dB * 256 + 16*l;
      uA0.u = *(const uint4*)pA; uA1.u = *(const uint4*)(pA + 8);
      uB0.u = *(const uint4*)pB; uB1.u = *(const uint4*)(pB + 8);
#pragma unroll
      for (int j = 0; j < 4; j++){
        float2 xa = __half22float2(uA0.h[j]);
        float2 xb = __half22float2(uB0.h[j]);
        acc[2*j]   += wA*xa.x + wB*xb.x;
        acc[2*j+1] += wA*xa.y + wB*xb.y;
        float2 ya = __half22float2(uA1.h[j]);
        float2 yb = __half22float2(uB1.h[j]);
        acc[8+2*j]   += wA*ya.x + wB*yb.x;
        acc[8+2*j+1] += wA*ya.y + wB*yb.y;
      }
    }
    if (e < cnt){
      int dA = sc[wave][g*16 + e];
      float wA = sw[wave][g*16 + e][hh];
      U4 uA0, uA1;
      const __half* pA = ht2 + (size_t)dA * 256 + 16*l;
      uA0.u = *(const uint4*)pA; uA1.u = *(const uint4*)(pA + 8);
#pragma unroll
      for (int j = 0; j < 4; j++){
        float2 xa = __half22float2(uA0.h[j]);
        acc[2*j]   += wA*xa.x;
        acc[2*j+1] += wA*xa.y;
        float2 ya = __half22float2(uA1.h[j]);
        acc[8+2*j]   += wA*ya.x;
        acc[8+2*j+1] += wA*ya.y;
      }
    }
    __builtin_amdgcn_wave_barrier();
  }
  float ssel = (hh==0)?s0:(hh==1)?s1:(hh==2)?s2:s3;
  float rinv = 1.f / (ssel + 1e-16f);
  float mj[16]; float sum2 = 0.f;
#pragma unroll
  for (int j = 0; j < 16; j++){
    float v = acc[j] * rinv;
    v += __shfl_xor(v, 4, 64);
    v += __shfl_xor(v, 8, 64);
    mj[j] = 0.25f * v;
    sum2 = fmaf(mj[j], mj[j], sum2);
  }
  sum2 = 0.25f * gsum16(sum2);
  float nn = fmaxf(sqrtf(sum2), MINNRM);
  float un = tanhf(nn);
  float f_, uN;
  if (un > MAXN){ f_ = MAXN / nn; uN = MAXN; } else { f_ = un / nn; uN = un; }
  float lg = artanh_c(uN) / fmaxf(uN, MINNRM);
  float tt[16]; float sum2b = 0.f;
#pragma unroll
  for (int j = 0; j < 16; j++){ tt[j] = lrelu(mj[j] * f_ * lg, 0.01f); sum2b = fmaf(tt[j], tt[j], sum2b); }
  sum2b = 0.25f * gsum16(sum2b);
  float nn2 = fmaxf(sqrtf(sum2b), MINNRM);
  float un2 = tanhf(nn2);
  float f2 = (un2 > MAXN) ? (MAXN / nn2) : (un2 / nn2);
  float uN2 = fminf(un2, MAXN);
  float lg2 = artanh_c(uN2) / fmaxf(uN2, MINNRM);
  if (hh == 0){
    float o[16];
#pragma unroll
    for (int j = 0; j < 16; j++) o[j] = tt[j] * f2 * lg2;
    float* op = out + (size_t)n * 64 + 16*l;
    *(float4*)op      = *(float4*)&o[0];
    *(float4*)(op+4)  = *(float4*)&o[4];
    *(float4*)(op+8)  = *(float4*)&o[8];
    *(float4*)(op+12) = *(float4*)&o[12];
  }
}

extern "C" void kernel_launch(void* const* d_in, const int* in_sizes, int n_in,
                              void* d_out, int out_size, void* d_ws, size_t ws_size,
                              hipStream_t stream){
  const float* x   = (const float*)d_in[0];
  const float* Wl  = (const float*)d_in[1];
  const float* bl  = (const float*)d_in[2];
  const float* W1  = (const float*)d_in[3];
  const float* b1  = (const float*)d_in[4];
  const float* ai1 = (const float*)d_in[5];
  const float* aj1 = (const float*)d_in[6];
  const float* W2  = (const float*)d_in[7];
  const float* b2  = (const float*)d_in[8];
  const float* ai2 = (const float*)d_in[9];
  const float* aj2 = (const float*)d_in[10];
  const int*   ei  = (const int*)d_in[11];
  float* out = (float*)d_out;
  float* ws  = (float*)d_ws;

  float* h0     = ws;                       // [0, 3.2M)
  __half* ht1h  = (__half*)(ws + 3200000);  // 6.4M halves
  float* hact   = ws + 6400000;             // [6.4M, 12.8M)
  __half* ht2h  = (__half*)(ws + 12800000); // 12.8M halves
  float* xn0    = ws + 19200000;
  float* xn1    = ws + 19250000;
  float* s1i    = ws + 19300000;  // also s2i
  float* s1j    = ws + 19500000;  // also s2j
  float* hbx1   = ws + 19700000;  // 137 (pad 144)
  float* hbx2   = ws + 19700144;  // 265
  int* rowptr   = (int*)(ws + 19700416);  // NN+1
  int* cnt      = rowptr + NN + 1;        // NN (fill cursor)
  int* col      = cnt + NN;               // NE
  int* part     = col + NE;               // NN
  int* bsum     = part + NN;              // NBLK
  float* Wlt    = ws + 20800000;          // 8192
  float* W1t    = ws + 20810000;          // 8192
  float* W2t    = ws + 20820000;          // 32768

  hipMemsetAsync(cnt, 0, NN * sizeof(int), stream);
  kbias2<<<1, 256, 0, stream>>>(b1, ai1, aj1, 128, 32, hbx1);
  kbias2<<<1, 256, 0, stream>>>(b2, ai2, aj2, 256, 64, hbx2);
  kT<<<32, 256, 0, stream>>>(Wl, Wlt, 64, 128);
  kT<<<32, 256, 0, stream>>>(W1, W1t, 128, 64);
  kT<<<128, 256, 0, stream>>>(W2, W2t, 256, 128);
  khist<<<(NE + 255) / 256, 256, 0, stream>>>(ei, cnt);
  kscan1<<<NBLK, SCAN_B, 0, stream>>>(cnt, part, bsum);
  kscan2<<<1, 128, 0, stream>>>(bsum);
  kscan3<<<NBLK, SCAN_B, 0, stream>>>(part, bsum, rowptr, cnt);
  kfill<<<(NE + 255) / 256, 256, 0, stream>>>(ei, cnt, col);
  k_g0<<<(NN + 255) / 256, 256, 0, stream>>>(x, Wlt, bl, h0, xn0);
  kg1f<<<(NN + 127) / 128, 256, 0, stream>>>(h0, W1t, xn0, hbx1, ai1, aj1, ht1h, s1i, s1j);
  k_agg1<<<NN / 16, 256, 0, stream>>>(rowptr, col, ht1h, s1i, s1j, hact, xn1);
  kg2f<<<(NN + 63) / 64, 256, 0, stream>>>(hact, W2t, xn1, hbx2, ai2, aj2, ht2h, s1i, s1j);
  k_agg2<<<NN / 16, 256, 0, stream>>>(rowptr, col, ht2h, s1i, s1j, out);
}